// Round 4
// baseline (2177.151 us; speedup 1.0000x reference)
//
#include <hip/hip_runtime.h>
#include <hip/hip_cooperative_groups.h>
#include <hip/hip_bf16.h>

namespace cg = cooperative_groups;

#define MAXD 32
typedef __hip_bfloat16 bf16;

constexpr int NTOT = 54612;    // total rows across 6 levels
constexpr int ETOT = 327600;   // total edges
constexpr int NX0 = 40962 * 4;

__device__ __forceinline__ float bf2f(bf16 v) { return __bfloat162float(v); }
__device__ __forceinline__ float2 ldbf2(const bf16* p) {
  unsigned u = *(const unsigned*)p;
  return make_float2(__uint_as_float(u << 16), __uint_as_float(u & 0xffff0000u));
}
__device__ __forceinline__ float2 unpk(unsigned u) {
  return make_float2(__uint_as_float(u << 16), __uint_as_float(u & 0xffff0000u));
}
__device__ __forceinline__ unsigned pk2(float x, float y) {
  bf16 bx = __float2bfloat16(x), by = __float2bfloat16(y);
  unsigned short ux, uy;
  __builtin_memcpy(&ux, &bx, 2);
  __builtin_memcpy(&uy, &by, 2);
  return (unsigned)ux | ((unsigned)uy << 16);
}

struct EdgeParams {
  const int* e[6];
  int E[6];
  int ebase[6];
  int nbase[6];
};

struct VSrc {
  const float* hf; const bf16* hh;
  const float* skf; const bf16* skh;
  const int* up;
  int nprev, Ch, Cs;
};

__device__ __forceinline__ float vloadf(const VSrc& s, int i, int c) {
  if (s.up) {
    if (c >= s.Ch) return s.skf[(long)i * s.Cs + (c - s.Ch)];
    if (i >= s.nprev) {
      int j = i - s.nprev;
      int u0 = s.up[2 * j], u1 = s.up[2 * j + 1];
      return 0.5f * (s.hf[(long)u0 * s.Ch + c] + s.hf[(long)u1 * s.Ch + c]);
    }
    return s.hf[(long)i * s.Ch + c];
  }
  return s.hf[(long)i * s.Ch + c];
}

__device__ __forceinline__ float2 vloadh2(const VSrc& s, int i, int c2) {
  int c = 2 * c2;
  if (s.up) {
    if (c >= s.Ch) return ldbf2(s.skh + (long)i * s.Cs + (c - s.Ch));
    if (i >= s.nprev) {
      int j = i - s.nprev;
      int u0 = s.up[2 * j], u1 = s.up[2 * j + 1];
      float2 a = ldbf2(s.hh + (long)u0 * s.Ch + c);
      float2 b = ldbf2(s.hh + (long)u1 * s.Ch + c);
      return make_float2(0.5f * (a.x + b.x), 0.5f * (a.y + b.y));
    }
    return ldbf2(s.hh + (long)i * s.Ch + c);
  }
  return ldbf2(s.hh + (long)i * s.Ch + c);
}

__device__ __forceinline__ float2 vloadf2(const VSrc& s, int i, int c) {
  return make_float2(vloadf(s, i, c), vloadf(s, i, c + 1));
}

// Everything the mega kernel needs, by value (kernarg).
struct MegaP {
  EdgeParams ep;
  int* cnt; int2* ell;
  const float* wsrc[11]; float* wdst[11];
  int cin[11], cout[11], tot[11];
  int wtot;
  const float* x0f; bf16* x0h;
  float* t1f; bf16* t1h; bf16* t2h; bf16* xh;
  const float* bias[11];
  float* af[10]; bf16* ah[10];
  float* outp;
  const int* up[5];
};

// ---------------- stage bodies (shared by mega kernel and fallback) ----------------
__device__ void st_setup(const MegaP& P) {
  int TALL = NTOT + P.wtot + NX0;
  for (int idx = blockIdx.x * blockDim.x + threadIdx.x; idx < TALL; idx += gridDim.x * blockDim.x) {
    if (idx < NTOT) { P.cnt[idx] = 0; continue; }
    int off0 = idx - NTOT;
    if (off0 >= P.wtot) {
      int j = off0 - P.wtot;
      P.x0h[j] = __float2bfloat16(P.x0f[j]);
      continue;
    }
    int l = 0, off = off0;
    while (off >= P.tot[l]) { off -= P.tot[l]; ++l; }
    int cout = P.cout[l];
    int cinco = P.cin[l] * cout;
    int t = off / cinco;
    int rem = off - t * cinco;
    int k = rem / cout;
    int o = rem - k * cout;
    P.wdst[l][((t * (P.cin[l] >> 2) + (k >> 2)) * cout + o) * 4 + (k & 3)] = P.wsrc[l][off];
  }
}

__device__ void st_fill(const MegaP& P) {
  for (int idx = blockIdx.x * blockDim.x + threadIdx.x; idx < ETOT; idx += gridDim.x * blockDim.x) {
    int l;
    if (idx < P.ep.ebase[1]) l = 0;
    else if (idx < P.ep.ebase[2]) l = 1;
    else if (idx < P.ep.ebase[3]) l = 2;
    else if (idx < P.ep.ebase[4]) l = 3;
    else if (idx < P.ep.ebase[5]) l = 4;
    else l = 5;
    int e = idx - P.ep.ebase[l];
    const int* epp = P.ep.e[l];
    int row = epp[e];
    int col = epp[P.ep.E[l] + e];
    int g = P.ep.nbase[l] + row;
    int slot = atomicAdd(&P.cnt[g], 1);
    if (slot < MAXD) P.ell[g * MAXD + slot].x = col;
  }
}

__device__ void st_wfill(const MegaP& P) {
  int total = NTOT * MAXD;
  for (int idx = blockIdx.x * blockDim.x + threadIdx.x; idx < total; idx += gridDim.x * blockDim.x) {
    int g = idx >> 5;
    int t = idx & (MAXD - 1);
    int dg = P.cnt[g];
    int d = dg < MAXD ? dg : MAXD;
    if (t < d) {
      int l;
      if (g < P.ep.nbase[1]) l = 0;
      else if (g < P.ep.nbase[2]) l = 1;
      else if (g < P.ep.nbase[3]) l = 2;
      else if (g < P.ep.nbase[4]) l = 3;
      else if (g < P.ep.nbase[5]) l = 4;
      else l = 5;
      int c = P.ell[idx].x;
      int dc = P.cnt[P.ep.nbase[l] + c];
      float w = (dc > 0) ? -(rsqrtf((float)dg) * rsqrtf((float)dc)) : 0.0f;
      P.ell[idx].y = __float_as_int(w);
    }
  }
}

// big-layer t1 gather (2 rows/thread, 4 ch/thread, uint2-vectorized).
// Gather index clamped to slot 0 past degree (slot 0 of a degree-0 row is
// uninitialized poison otherwise).
__device__ void st_prop_flat(const MegaP& P, const bf16* __restrict__ Xh,
                             int nbase, int n, int C) {
  int C4 = C >> 2;
  int total = (n >> 1) * C4;
  const int* cnt = P.cnt; const int2* ell = P.ell; bf16* Th = P.t1h;
  for (int idx = blockIdx.x * blockDim.x + threadIdx.x; idx < total; idx += gridDim.x * blockDim.x) {
    int ip = idx / C4;
    int c = (idx - ip * C4) << 2;
    int i0 = ip << 1, i1 = i0 + 1;
    int g0 = nbase + i0, g1 = nbase + i1;
    int d0 = cnt[g0]; if (d0 > MAXD) d0 = MAXD;
    int d1 = cnt[g1]; if (d1 > MAXD) d1 = MAXD;
    const int2* cols0 = ell + (long)g0 * MAXD;
    const int2* cols1 = ell + (long)g1 * MAXD;
    float a0 = 0.f, a1 = 0.f, a2 = 0.f, a3 = 0.f;
    float b0 = 0.f, b1 = 0.f, b2 = 0.f, b3 = 0.f;
    int dm = d0 > d1 ? d0 : d1;
    for (int t = 0; t < dm; t += 8) {
      int ciA[8], ciB[8]; float wA[8], wB[8];
#pragma unroll
      for (int j = 0; j < 8; ++j) {
        int tt = t + j;
        int2 eA = cols0[(tt < d0) ? tt : 0];
        int2 eB = cols1[(tt < d1) ? tt : 0];
        ciA[j] = (tt < d0) ? eA.x : 0;
        wA[j] = (tt < d0) ? __int_as_float(eA.y) : 0.f;
        ciB[j] = (tt < d1) ? eB.x : 0;
        wB[j] = (tt < d1) ? __int_as_float(eB.y) : 0.f;
      }
#pragma unroll
      for (int j = 0; j < 8; ++j) {
        uint2 rA = *(const uint2*)(Xh + (long)ciA[j] * C + c);
        uint2 rB = *(const uint2*)(Xh + (long)ciB[j] * C + c);
        float2 vA01 = unpk(rA.x), vA23 = unpk(rA.y);
        float2 vB01 = unpk(rB.x), vB23 = unpk(rB.y);
        a0 += wA[j] * vA01.x; a1 += wA[j] * vA01.y; a2 += wA[j] * vA23.x; a3 += wA[j] * vA23.y;
        b0 += wB[j] * vB01.x; b1 += wB[j] * vB01.y; b2 += wB[j] * vB23.x; b3 += wB[j] * vB23.y;
      }
    }
    long o0 = (long)i0 * C + c;
    long o1 = (long)i1 * C + c;
    uint2 pA; pA.x = pk2(a0, a1); pA.y = pk2(a2, a3);
    uint2 pB; pB.x = pk2(b0, b1); pB.y = pk2(b2, b3);
    *(uint2*)(Th + o0) = pA;
    *(uint2*)(Th + o1) = pB;
  }
}

// t2 = 2*A~t1 - x
__device__ void st_prop2(const MegaP& P, const bf16* __restrict__ Xh,
                         int nbase, int n, int C) {
  int C4 = C >> 2;
  int total = (n >> 1) * C4;
  const int* cnt = P.cnt; const int2* ell = P.ell;
  const bf16* T1h = P.t1h; bf16* T2h = P.t2h;
  for (int idx = blockIdx.x * blockDim.x + threadIdx.x; idx < total; idx += gridDim.x * blockDim.x) {
    int ip = idx / C4;
    int c = (idx - ip * C4) << 2;
    int i0 = ip << 1, i1 = i0 + 1;
    int g0 = nbase + i0, g1 = nbase + i1;
    int d0 = cnt[g0]; if (d0 > MAXD) d0 = MAXD;
    int d1 = cnt[g1]; if (d1 > MAXD) d1 = MAXD;
    const int2* cols0 = ell + (long)g0 * MAXD;
    const int2* cols1 = ell + (long)g1 * MAXD;
    float a0 = 0.f, a1 = 0.f, a2 = 0.f, a3 = 0.f;
    float b0 = 0.f, b1 = 0.f, b2 = 0.f, b3 = 0.f;
    int dm = d0 > d1 ? d0 : d1;
    for (int t = 0; t < dm; t += 8) {
      int ciA[8], ciB[8]; float wA[8], wB[8];
#pragma unroll
      for (int j = 0; j < 8; ++j) {
        int tt = t + j;
        int2 eA = cols0[(tt < d0) ? tt : 0];
        int2 eB = cols1[(tt < d1) ? tt : 0];
        ciA[j] = (tt < d0) ? eA.x : 0;
        wA[j] = (tt < d0) ? __int_as_float(eA.y) : 0.f;
        ciB[j] = (tt < d1) ? eB.x : 0;
        wB[j] = (tt < d1) ? __int_as_float(eB.y) : 0.f;
      }
#pragma unroll
      for (int j = 0; j < 8; ++j) {
        uint2 rA = *(const uint2*)(T1h + (long)ciA[j] * C + c);
        uint2 rB = *(const uint2*)(T1h + (long)ciB[j] * C + c);
        float2 vA01 = unpk(rA.x), vA23 = unpk(rA.y);
        float2 vB01 = unpk(rB.x), vB23 = unpk(rB.y);
        a0 += wA[j] * vA01.x; a1 += wA[j] * vA01.y; a2 += wA[j] * vA23.x; a3 += wA[j] * vA23.y;
        b0 += wB[j] * vB01.x; b1 += wB[j] * vB01.y; b2 += wB[j] * vB23.x; b3 += wB[j] * vB23.y;
      }
    }
    long o0 = (long)i0 * C + c;
    long o1 = (long)i1 * C + c;
    uint2 xr0 = *(const uint2*)(Xh + o0);
    uint2 xr1 = *(const uint2*)(Xh + o1);
    float2 x001 = unpk(xr0.x), x023 = unpk(xr0.y);
    float2 x101 = unpk(xr1.x), x123 = unpk(xr1.y);
    uint2 pA; pA.x = pk2(2.f * a0 - x001.x, 2.f * a1 - x001.y); pA.y = pk2(2.f * a2 - x023.x, 2.f * a3 - x023.y);
    uint2 pB; pB.x = pk2(2.f * b0 - x101.x, 2.f * b1 - x101.y); pB.y = pk2(2.f * b2 - x123.x, 2.f * b3 - x123.y);
    *(uint2*)(T2h + o0) = pA;
    *(uint2*)(T2h + o1) = pB;
  }
}

// mid-layer t1 gather from virtual source
__device__ void st_prop_v(const MegaP& P, VSrc src, int nbase, int n, int C) {
  int C2 = C >> 1;
  int total = n * C2;
  const int* cnt = P.cnt; const int2* ell = P.ell;
  float* T = P.t1f; bf16* Th = P.t1h;
  for (int idx = blockIdx.x * blockDim.x + threadIdx.x; idx < total; idx += gridDim.x * blockDim.x) {
    int i = idx / C2;
    int c2 = idx - i * C2;
    int g = nbase + i;
    int d = cnt[g]; if (d > MAXD) d = MAXD;
    const int2* cols = ell + (long)g * MAXD;
    float ax = 0.f, ay = 0.f;
    for (int t = 0; t < d; t += 8) {
      int ci[8]; float wj[8];
#pragma unroll
      for (int j = 0; j < 8; ++j) {
        int tt = t + j;
        int2 e = cols[(tt < d) ? tt : 0];
        ci[j] = e.x;
        wj[j] = (tt < d) ? __int_as_float(e.y) : 0.f;
      }
#pragma unroll
      for (int j = 0; j < 8; ++j) {
        float2 v = vloadh2(src, ci[j], c2);
        ax += wj[j] * v.x;
        ay += wj[j] * v.y;
      }
    }
    long o = (long)i * C + 2 * c2;
    ((float2*)T)[o >> 1] = make_float2(ax, ay);
    *(unsigned*)(Th + o) = pk2(ax, ay);
  }
}

__device__ void st_xmat(VSrc src, bf16* __restrict__ Xh, int n, int Ctot) {
  int C2 = Ctot >> 1;
  int total = n * C2;
  for (int idx = blockIdx.x * blockDim.x + threadIdx.x; idx < total; idx += gridDim.x * blockDim.x) {
    int i = idx / C2;
    int c2 = idx - i * C2;
    float2 v = vloadf2(src, i, 2 * c2);
    *(unsigned*)(Xh + (long)i * Ctot + 2 * c2) = pk2(v.x, v.y);
  }
}

// big-layer combine, 16 rows/tile (per-wave LDS partitions -> tile loop safe)
template <int SMAX>
__device__ void st_combine_big(float* smem, const bf16* __restrict__ Xh,
                               const bf16* __restrict__ T1h, const bf16* __restrict__ T2h,
                               const float4* __restrict__ Wp, const float* __restrict__ B,
                               int n, int Cin, int Cout,
                               float* __restrict__ OUT, bf16* __restrict__ OUTh) {
  constexpr int RPW = 4;
  float* sx = smem;
  float* st1 = smem + 4 * RPW * 64;
  float* st2 = smem + 8 * RPW * 64;
  int tid = threadIdx.x;
  int w = tid >> 6;
  int lane = tid & 63;
  int colTiles = (Cout + 63) >> 6;
  int rowTiles = (n + 4 * RPW - 1) / (4 * RPW);
  int tiles = colTiles * rowTiles;
  int nch = (Cin + 63) >> 6;
  int KQ = Cin >> 2;

  for (int bt = blockIdx.x; bt < tiles; bt += gridDim.x) {
    int ct = bt % colTiles;
    int rt = bt / colTiles;
    int r0 = rt * (4 * RPW) + w * RPW;
    int o = ct * 64 + lane;
    int oc = (o < Cout) ? o : (Cout - 1);

    float acc[RPW];
#pragma unroll
    for (int r = 0; r < RPW; ++r) acc[r] = 0.f;

    for (int c = 0; c < nch; ++c) {
      int k0 = c * 64;
      int kw = (Cin - k0 < 64) ? (Cin - k0) : 64;
      int k = k0 + lane;
      bool kv = lane < kw;
#pragma unroll
      for (int rr = 0; rr < RPW; ++rr) {
        int i = r0 + rr;
        bool iv = i < n;
        float xv = 0.f, tv = 0.f, t2v = 0.f;
        if (kv && iv) {
          long off = (long)i * Cin + k;
          xv = bf2f(Xh[off]);
          tv = bf2f(T1h[off]);
          t2v = bf2f(T2h[off]);
        }
        sx[(w * RPW + rr) * 64 + lane] = xv;
        st1[(w * RPW + rr) * 64 + lane] = tv;
        st2[(w * RPW + rr) * 64 + lane] = t2v;
      }
      __syncthreads();
      int kw4 = kw >> 2;
      for (int q = 0; q < kw4; ++q) {
        int kq = (k0 >> 2) + q;
        float4 w0 = Wp[(0 * KQ + kq) * Cout + oc];
        float4 w1 = Wp[(1 * KQ + kq) * Cout + oc];
        float4 w2 = Wp[(2 * KQ + kq) * Cout + oc];
#pragma unroll
        for (int rr = 0; rr < RPW; ++rr) {
          float4 xs = ((const float4*)(sx + (w * RPW + rr) * 64))[q];
          float4 t1s = ((const float4*)(st1 + (w * RPW + rr) * 64))[q];
          float4 t2s = ((const float4*)(st2 + (w * RPW + rr) * 64))[q];
          acc[rr] += w0.x * xs.x + w0.y * xs.y + w0.z * xs.z + w0.w * xs.w;
          acc[rr] += w1.x * t1s.x + w1.y * t1s.y + w1.z * t1s.z + w1.w * t1s.w;
          acc[rr] += w2.x * t2s.x + w2.y * t2s.y + w2.z * t2s.z + w2.w * t2s.w;
        }
      }
      __syncthreads();
    }

    if constexpr (SMAX) {
      float bb = (o < Cout) ? B[o] : 0.f;
#pragma unroll
      for (int rr = 0; rr < RPW; ++rr) {
        int i = r0 + rr;
        if (i < n) {
          float v = (o < Cout) ? (acc[rr] + bb) : -1e30f;
          float m = v;
          for (int s = 32; s > 0; s >>= 1) m = fmaxf(m, __shfl_xor(m, s));
          float e = (o < Cout) ? __expf(v - m) : 0.f;
          float sum = e;
          for (int s = 32; s > 0; s >>= 1) sum += __shfl_xor(sum, s);
          if (o < Cout) OUT[(long)i * Cout + o] = e / sum;
        }
      }
    } else {
      if (o < Cout) {
        float bb = B[oc];
#pragma unroll
        for (int rr = 0; rr < RPW; ++rr) {
          int i = r0 + rr;
          if (i < n) {
            float v = fmaxf(acc[rr] + bb, 0.f);
            long off = (long)i * Cout + o;
            OUT[off] = v;
            OUTh[off] = __float2bfloat16(v);
          }
        }
      }
    }
  }
}

// mid-layer combine, t2 gathered inline; simple W loop (no deep preload:
// round-1 lesson — preload spilled at 128-VGPR budgets).
template <int ROWS, int CW>
__device__ void st_combine_mid(float* smem, VSrc src,
                               const float* __restrict__ T1, const bf16* __restrict__ T1h,
                               const float4* __restrict__ Wp, const float* __restrict__ B,
                               const int* __restrict__ cnt, const int2* __restrict__ ell,
                               int nbase, int n, int Cin, int Cout,
                               float* __restrict__ OUT, bf16* __restrict__ OUTh) {
  constexpr int RPW = (ROWS * CW) / 4;
  static_assert(RPW * (4 / CW) == ROWS, "bad ROWS/CW combo");
  float* sx = smem;
  float* st1s = smem + 4 * RPW * 64;
  float* st2s = smem + 8 * RPW * 64;
  int tid = threadIdx.x;
  int w = tid >> 6;
  int lane = tid & 63;
  int rg = w / CW;
  int cw = w % CW;
  int colTiles = (Cout + 63) >> 6;
  int rowTiles = (n + ROWS - 1) / ROWS;
  int tiles = colTiles * rowTiles;
  int nch = (Cin + 63) >> 6;
  int KQ = Cin >> 2;

  for (int bt = blockIdx.x; bt < tiles; bt += gridDim.x) {
    int ct = bt % colTiles;
    int rt = bt / colTiles;
    int r0 = rt * ROWS + rg * RPW;
    int o = ct * 64 + lane;
    int oc = (o < Cout) ? o : (Cout - 1);

    float acc[RPW];
#pragma unroll
    for (int r = 0; r < RPW; ++r) acc[r] = 0.f;

    for (int cg = 0; cg < nch; cg += CW) {
      int c = cg + cw;
      bool act = c < nch;
      int k0 = c * 64;
      int kw = act ? ((Cin - k0 < 64) ? (Cin - k0) : 64) : 0;
      int k = k0 + lane;
      bool kv = act && (lane < kw);
#pragma unroll
      for (int rr = 0; rr < RPW; ++rr) {
        int i = r0 + rr;
        bool iv = i < n;
        float xv = 0.f, tv = 0.f, t2v = 0.f;
        if (kv && iv) {
          xv = vloadf(src, i, k);
          tv = T1[(long)i * Cin + k];
          int g = nbase + i;
          int d = cnt[g]; if (d > MAXD) d = MAXD;
          const int2* cols = ell + (long)g * MAXD;
          float a2 = 0.f;
          for (int t = 0; t < d; t += 8) {
            int ci[8]; float wj[8];
#pragma unroll
            for (int j = 0; j < 8; ++j) {
              int tt = t + j;
              int2 e = cols[(tt < d) ? tt : 0];
              ci[j] = e.x;
              wj[j] = (tt < d) ? __int_as_float(e.y) : 0.f;
            }
#pragma unroll
            for (int j = 0; j < 8; ++j)
              a2 += wj[j] * bf2f(T1h[(long)ci[j] * Cin + k]);
          }
          t2v = 2.f * a2 - xv;
        }
        sx[(w * RPW + rr) * 64 + lane] = xv;
        st1s[(w * RPW + rr) * 64 + lane] = tv;
        st2s[(w * RPW + rr) * 64 + lane] = t2v;
      }
      __syncthreads();
      int kw4 = kw >> 2;
      int kqb = k0 >> 2;
      for (int q = 0; q < kw4; ++q) {
        int kq = kqb + q;
        float4 w0 = Wp[(0 * KQ + kq) * Cout + oc];
        float4 w1 = Wp[(1 * KQ + kq) * Cout + oc];
        float4 w2 = Wp[(2 * KQ + kq) * Cout + oc];
#pragma unroll
        for (int rr = 0; rr < RPW; ++rr) {
          float4 xs = ((const float4*)(sx + (w * RPW + rr) * 64))[q];
          float4 t1s = ((const float4*)(st1s + (w * RPW + rr) * 64))[q];
          float4 t2s = ((const float4*)(st2s + (w * RPW + rr) * 64))[q];
          acc[rr] += w0.x * xs.x + w0.y * xs.y + w0.z * xs.z + w0.w * xs.w;
          acc[rr] += w1.x * t1s.x + w1.y * t1s.y + w1.z * t1s.z + w1.w * t1s.w;
          acc[rr] += w2.x * t2s.x + w2.y * t2s.y + w2.z * t2s.z + w2.w * t2s.w;
        }
      }
      __syncthreads();
    }

    if constexpr (CW == 1) {
      if (o < Cout) {
        float bb = B[oc];
#pragma unroll
        for (int rr = 0; rr < RPW; ++rr) {
          int i = r0 + rr;
          if (i < n) {
            float v = fmaxf(acc[rr] + bb, 0.f);
            long off = (long)i * Cout + o;
            OUT[off] = v;
            OUTh[off] = __float2bfloat16(v);
          }
        }
      }
    } else {
#pragma unroll
      for (int rr = 0; rr < RPW; ++rr) sx[(w * RPW + rr) * 64 + lane] = acc[rr];
      __syncthreads();
      if (cw == 0 && o < Cout) {
        float bb = B[oc];
#pragma unroll
        for (int rr = 0; rr < RPW; ++rr) {
          int i = r0 + rr;
          if (i < n) {
            float v = bb;
#pragma unroll
            for (int j = 0; j < CW; ++j) v += sx[((rg * CW + j) * RPW + rr) * 64 + lane];
            v = fmaxf(v, 0.f);
            long off = (long)i * Cout + o;
            OUT[off] = v;
            OUTh[off] = __float2bfloat16(v);
          }
        }
      }
      __syncthreads();  // protect sx before next tile's staging
    }
  }
}

// ---------------- virtual-source builders (device + host usable) ----------------
__host__ __device__ inline VSrc mkplain(const float* hf, const bf16* hh, int Ch) {
  VSrc s{hf, hh, nullptr, nullptr, nullptr, 0, Ch, 0}; return s;
}
__host__ __device__ inline VSrc mkup(const float* hf, const bf16* hh, const float* skf,
                                     const bf16* skh, const int* u, int nprev, int Ch, int Cs) {
  VSrc s{hf, hh, skf, skh, u, nprev, Ch, Cs}; return s;
}

// ---------------- the mega kernel ----------------
__global__ __launch_bounds__(256, 4) void k_mega(MegaP P) {
  cg::grid_group gg = cg::this_grid();
  __shared__ __align__(16) float smem[3 * 4 * 4 * 64];  // 12 KB, max over stages

  st_setup(P); gg.sync();
  st_fill(P); gg.sync();
  st_wfill(P); gg.sync();

  // L1: 40962, 4->32
  st_prop_flat(P, P.x0h, P.ep.nbase[5], 40962, 4); gg.sync();
  st_prop2(P, P.x0h, P.ep.nbase[5], 40962, 4); gg.sync();
  st_combine_big<0>(smem, P.x0h, P.t1h, P.t2h, (const float4*)P.wdst[0], P.bias[0],
                    40962, 4, 32, P.af[0], P.ah[0]); gg.sync();
  // L2: 10242, 32->64
  st_prop_flat(P, P.ah[0], P.ep.nbase[4], 10242, 32); gg.sync();
  st_prop2(P, P.ah[0], P.ep.nbase[4], 10242, 32); gg.sync();
  st_combine_big<0>(smem, P.ah[0], P.t1h, P.t2h, (const float4*)P.wdst[1], P.bias[1],
                    10242, 32, 64, P.af[1], P.ah[1]); gg.sync();
  // L3: 2562, 64->128
  {
    VSrc s = mkplain(P.af[1], P.ah[1], 64);
    st_prop_v(P, s, P.ep.nbase[3], 2562, 64); gg.sync();
    st_combine_mid<4, 1>(smem, s, P.t1f, P.t1h, (const float4*)P.wdst[2], P.bias[2],
                         P.cnt, P.ell, P.ep.nbase[3], 2562, 64, 128, P.af[2], P.ah[2]); gg.sync();
  }
  // L4: 642, 128->256
  {
    VSrc s = mkplain(P.af[2], P.ah[2], 128);
    st_prop_v(P, s, P.ep.nbase[2], 642, 128); gg.sync();
    st_combine_mid<2, 2>(smem, s, P.t1f, P.t1h, (const float4*)P.wdst[3], P.bias[3],
                         P.cnt, P.ell, P.ep.nbase[2], 642, 128, 256, P.af[3], P.ah[3]); gg.sync();
  }
  // L5: 162, 256->512
  {
    VSrc s = mkplain(P.af[3], P.ah[3], 256);
    st_prop_v(P, s, P.ep.nbase[1], 162, 256); gg.sync();
    st_combine_mid<1, 4>(smem, s, P.t1f, P.t1h, (const float4*)P.wdst[4], P.bias[4],
                         P.cnt, P.ell, P.ep.nbase[1], 162, 256, 512, P.af[4], P.ah[4]); gg.sync();
  }
  // L6: 42, 512->512
  {
    VSrc s = mkplain(P.af[4], P.ah[4], 512);
    st_prop_v(P, s, P.ep.nbase[0], 42, 512); gg.sync();
    st_combine_mid<1, 4>(smem, s, P.t1f, P.t1h, (const float4*)P.wdst[5], P.bias[5],
                         P.cnt, P.ell, P.ep.nbase[0], 42, 512, 512, P.af[5], P.ah[5]); gg.sync();
  }
  // L7: 162, [512|256]->256
  {
    VSrc s = mkup(P.af[5], P.ah[5], P.af[3], P.ah[3], P.up[0], 42, 512, 256);
    st_prop_v(P, s, P.ep.nbase[1], 162, 768); gg.sync();
    st_combine_mid<1, 4>(smem, s, P.t1f, P.t1h, (const float4*)P.wdst[6], P.bias[6],
                         P.cnt, P.ell, P.ep.nbase[1], 162, 768, 256, P.af[6], P.ah[6]); gg.sync();
  }
  // L8: 642, [256|128]->128
  {
    VSrc s = mkup(P.af[6], P.ah[6], P.af[2], P.ah[2], P.up[1], 162, 256, 128);
    st_prop_v(P, s, P.ep.nbase[2], 642, 384); gg.sync();
    st_combine_mid<2, 4>(smem, s, P.t1f, P.t1h, (const float4*)P.wdst[7], P.bias[7],
                         P.cnt, P.ell, P.ep.nbase[2], 642, 384, 128, P.af[7], P.ah[7]); gg.sync();
  }
  // L9: 2562, [128|64]->64
  {
    VSrc s = mkup(P.af[7], P.ah[7], P.af[1], P.ah[1], P.up[2], 642, 128, 64);
    st_prop_v(P, s, P.ep.nbase[3], 2562, 192); gg.sync();
    st_combine_mid<2, 4>(smem, s, P.t1f, P.t1h, (const float4*)P.wdst[8], P.bias[8],
                         P.cnt, P.ell, P.ep.nbase[3], 2562, 192, 64, P.af[8], P.ah[8]); gg.sync();
  }
  // L10: 10242, [64|32]->32
  {
    VSrc s = mkup(P.af[8], P.ah[8], P.af[0], P.ah[0], P.up[3], 2562, 64, 32);
    st_xmat(s, P.xh, 10242, 96); gg.sync();
    st_prop_flat(P, P.xh, P.ep.nbase[4], 10242, 96); gg.sync();
    st_prop2(P, P.xh, P.ep.nbase[4], 10242, 96); gg.sync();
    st_combine_big<0>(smem, P.xh, P.t1h, P.t2h, (const float4*)P.wdst[9], P.bias[9],
                      10242, 96, 32, P.af[9], P.ah[9]); gg.sync();
  }
  // L11: 40962, [32|4]->37 + softmax
  {
    VSrc s = mkup(P.af[9], P.ah[9], P.x0f, P.x0h, P.up[4], 10242, 32, 4);
    st_xmat(s, P.xh, 40962, 36); gg.sync();
    st_prop_flat(P, P.xh, P.ep.nbase[5], 40962, 36); gg.sync();
    st_prop2(P, P.xh, P.ep.nbase[5], 40962, 36); gg.sync();
    st_combine_big<1>(smem, P.xh, P.t1h, P.t2h, (const float4*)P.wdst[10], P.bias[10],
                      40962, 36, 37, (float*)P.outp, (bf16*)nullptr);
  }
}

// ---------------- fallback wrappers (round-2 proven multi-launch path) ----------------
__global__ __launch_bounds__(256) void g_setup(MegaP P) { st_setup(P); }
__global__ __launch_bounds__(256) void g_fill(MegaP P) { st_fill(P); }
__global__ __launch_bounds__(256) void g_wfill(MegaP P) { st_wfill(P); }
__global__ __launch_bounds__(256) void g_prop_flat(MegaP P, const bf16* Xh, int nbase, int n, int C) {
  st_prop_flat(P, Xh, nbase, n, C);
}
__global__ __launch_bounds__(256) void g_prop2(MegaP P, const bf16* Xh, int nbase, int n, int C) {
  st_prop2(P, Xh, nbase, n, C);
}
__global__ __launch_bounds__(256) void g_prop_v(MegaP P, VSrc src, int nbase, int n, int C) {
  st_prop_v(P, src, nbase, n, C);
}
__global__ __launch_bounds__(256) void g_xmat(VSrc src, bf16* Xh, int n, int C) {
  st_xmat(src, Xh, n, C);
}
template <int SMAX>
__global__ __launch_bounds__(256) void g_combine_big(const bf16* Xh, const bf16* T1h, const bf16* T2h,
                                                     const float4* Wp, const float* B,
                                                     int n, int Cin, int Cout,
                                                     float* OUT, bf16* OUTh) {
  __shared__ __align__(16) float smem[3 * 4 * 4 * 64];
  st_combine_big<SMAX>(smem, Xh, T1h, T2h, Wp, B, n, Cin, Cout, OUT, OUTh);
}
template <int ROWS, int CW>
__global__ __launch_bounds__(256) void g_combine_mid(VSrc src, const float* T1, const bf16* T1h,
                                                     const float4* Wp, const float* B,
                                                     const int* cnt, const int2* ell,
                                                     int nbase, int n, int Cin, int Cout,
                                                     float* OUT, bf16* OUTh) {
  __shared__ __align__(16) float smem[3 * 4 * ((ROWS * CW) / 4) * 64];
  st_combine_mid<ROWS, CW>(smem, src, T1, T1h, Wp, B, cnt, ell, nbase, n, Cin, Cout, OUT, OUTh);
}

// ---------------- launcher ----------------
extern "C" void kernel_launch(void* const* d_in, const int* in_sizes, int n_in,
                              void* d_out, int out_size, void* d_ws, size_t ws_size,
                              hipStream_t stream) {
  static const int NV[6] = {42, 162, 642, 2562, 10242, 40962};
  static const int NE[6] = {240, 960, 3840, 15360, 61440, 245760};
  static const int LCI[11] = {4, 32, 64, 128, 256, 512, 768, 384, 192, 96, 36};
  static const int LCO[11] = {32, 64, 128, 256, 512, 512, 256, 128, 64, 32, 37};

  MegaP P;
  {
    int nb = 0, eb = 0;
    for (int l = 0; l < 6; ++l) {
      P.ep.e[l] = (const int*)d_in[1 + l];
      P.ep.E[l] = NE[l];
      P.ep.ebase[l] = eb;
      P.ep.nbase[l] = nb;
      eb += NE[l];
      nb += NV[l];
    }
  }
  P.x0f = (const float*)d_in[0];
  for (int i = 0; i < 5; ++i) P.up[i] = (const int*)d_in[7 + i];
  for (int i = 0; i < 11; ++i) {
    P.wsrc[i] = (const float*)d_in[12 + 2 * i];
    P.bias[i] = (const float*)d_in[13 + 2 * i];
    P.cin[i] = LCI[i];
    P.cout[i] = LCO[i];
    P.tot[i] = 3 * LCI[i] * LCO[i];
  }
  P.wtot = 0;
  for (int i = 0; i < 11; ++i) P.wtot += P.tot[i];
  P.outp = (float*)d_out;

  // ---- workspace carve (16B-aligned) ----
  char* p = (char*)d_ws;
  auto alloc_b = [&](size_t bytes) { void* r = (void*)p; p += (bytes + 15) & ~size_t(15); return r; };
  P.cnt = (int*)alloc_b((size_t)NTOT * 4);
  P.ell = (int2*)alloc_b((size_t)NTOT * MAXD * 8);
  P.t1f = (float*)alloc_b((size_t)40962 * 36 * 4);
  P.t1h = (bf16*)alloc_b((size_t)40962 * 36 * 2);
  P.t2h = (bf16*)alloc_b((size_t)40962 * 36 * 2);
  P.x0h = (bf16*)alloc_b((size_t)40962 * 4 * 2);
  P.xh = (bf16*)alloc_b((size_t)40962 * 36 * 2);
  for (int i = 0; i < 11; ++i) P.wdst[i] = (float*)alloc_b((size_t)3 * LCI[i] * LCO[i] * 4);
  const int an[10] = {40962, 10242, 2562, 642, 162, 42, 162, 642, 2562, 10242};
  const int ac[10] = {32, 64, 128, 256, 512, 512, 256, 128, 64, 32};
  for (int i = 0; i < 10; ++i) {
    P.af[i] = (float*)alloc_b((size_t)an[i] * ac[i] * 4);
    P.ah[i] = (bf16*)alloc_b((size_t)an[i] * ac[i] * 2);
  }

  // ---- try cooperative mega-kernel ----
  static int coopGrid = -2;  // -2 unqueried, -1 unusable
  if (coopGrid == -2) {
    int nb = 0;
    hipError_t qe = hipOccupancyMaxActiveBlocksPerMultiprocessor(&nb, (const void*)k_mega, 256, 0);
    if (qe == hipSuccess && nb > 0) {
      long g = (long)nb * 256;  // 256 CUs on MI355X
      coopGrid = (int)(g > 1024 ? 1024 : g);
    } else {
      (void)hipGetLastError();
      coopGrid = -1;
    }
  }
  bool done = false;
  if (coopGrid > 0) {
    void* args[] = {(void*)&P};
    hipError_t err = hipLaunchCooperativeKernel((const void*)k_mega, dim3(coopGrid), dim3(256),
                                                args, 0, stream);
    if (err == hipSuccess) done = true;
    else (void)hipGetLastError();
  }
  if (done) return;

  // ---- fallback: round-2 proven multi-launch sequence ----
  auto cb = [&](const bf16* Xh, int lvl, int n, int Cin, int Cout, int wi,
                float* OUT, bf16* OUTh, int smax) {
    int nb = P.ep.nbase[lvl];
    int t4p = (n >> 1) * (Cin >> 2);
    g_prop_flat<<<(t4p + 255) / 256, 256, 0, stream>>>(P, Xh, nb, n, Cin);
    g_prop2<<<(t4p + 255) / 256, 256, 0, stream>>>(P, Xh, nb, n, Cin);
    int grid = ((Cout + 63) / 64) * ((n + 15) / 16);
    if (smax)
      g_combine_big<1><<<grid, 256, 0, stream>>>(Xh, P.t1h, P.t2h, (const float4*)P.wdst[wi],
                                                 P.bias[wi], n, Cin, Cout, OUT, OUTh);
    else
      g_combine_big<0><<<grid, 256, 0, stream>>>(Xh, P.t1h, P.t2h, (const float4*)P.wdst[wi],
                                                 P.bias[wi], n, Cin, Cout, OUT, OUTh);
  };

  g_setup<<<(NTOT + P.wtot + NX0 + 255) / 256, 256, 0, stream>>>(P);
  g_fill<<<(ETOT + 255) / 256, 256, 0, stream>>>(P);
  g_wfill<<<(NTOT * MAXD + 255) / 256, 256, 0, stream>>>(P);

  cb(P.x0h, 5, 40962, 4, 32, 0, P.af[0], P.ah[0], 0);
  cb(P.ah[0], 4, 10242, 32, 64, 1, P.af[1], P.ah[1], 0);

#define MIDF(RS, CWv, s, lvl, n, Cin, Cout, wi, OUT, OUTh)                                       \
  {                                                                                              \
    int nb = P.ep.nbase[lvl];                                                                    \
    int t2n = (n) * ((Cin) >> 1);                                                                \
    g_prop_v<<<(t2n + 255) / 256, 256, 0, stream>>>(P, s, nb, n, Cin);                           \
    int grid = (((Cout) + 63) / 64) * (((n) + (RS)-1) / (RS));                                   \
    g_combine_mid<RS, CWv><<<grid, 256, 0, stream>>>(s, P.t1f, P.t1h,                            \
                                                     (const float4*)P.wdst[wi], P.bias[wi],      \
                                                     P.cnt, P.ell, nb, n, Cin, Cout, OUT, OUTh); \
  }

  MIDF(4, 1, mkplain(P.af[1], P.ah[1], 64), 3, 2562, 64, 128, 2, P.af[2], P.ah[2]);
  MIDF(2, 2, mkplain(P.af[2], P.ah[2], 128), 2, 642, 128, 256, 3, P.af[3], P.ah[3]);
  MIDF(1, 4, mkplain(P.af[3], P.ah[3], 256), 1, 162, 256, 512, 4, P.af[4], P.ah[4]);
  MIDF(1, 4, mkplain(P.af[4], P.ah[4], 512), 0, 42, 512, 512, 5, P.af[5], P.ah[5]);
  MIDF(1, 4, mkup(P.af[5], P.ah[5], P.af[3], P.ah[3], P.up[0], 42, 512, 256), 1, 162, 768, 256, 6, P.af[6], P.ah[6]);
  MIDF(2, 4, mkup(P.af[6], P.ah[6], P.af[2], P.ah[2], P.up[1], 162, 256, 128), 2, 642, 384, 128, 7, P.af[7], P.ah[7]);
  MIDF(2, 4, mkup(P.af[7], P.ah[7], P.af[1], P.ah[1], P.up[2], 642, 128, 64), 3, 2562, 192, 64, 8, P.af[8], P.ah[8]);

  {
    VSrc s = mkup(P.af[8], P.ah[8], P.af[0], P.ah[0], P.up[3], 2562, 64, 32);
    g_xmat<<<(10242 * 48 + 255) / 256, 256, 0, stream>>>(s, P.xh, 10242, 96);
    cb(P.xh, 4, 10242, 96, 32, 9, P.af[9], P.ah[9], 0);
  }
  {
    VSrc s = mkup(P.af[9], P.ah[9], P.x0f, P.x0h, P.up[4], 10242, 32, 4);
    g_xmat<<<(40962 * 18 + 255) / 256, 256, 0, stream>>>(s, P.xh, 40962, 36);
    cb(P.xh, 5, 40962, 36, 37, 10, (float*)d_out, (bf16*)nullptr, 1);
  }
}

// Round 5
// 522.062 us; speedup vs baseline: 4.1703x; 4.1703x over previous
//
#include <hip/hip_runtime.h>
#include <hip/hip_bf16.h>

#define MAXD 32
typedef __hip_bfloat16 bf16;

__device__ __forceinline__ float bf2f(bf16 v) { return __bfloat162float(v); }
__device__ __forceinline__ float2 ldbf2(const bf16* p) {
  unsigned u = *(const unsigned*)p;
  return make_float2(__uint_as_float(u << 16), __uint_as_float(u & 0xffff0000u));
}
__device__ __forceinline__ float2 unpk(unsigned u) {
  return make_float2(__uint_as_float(u << 16), __uint_as_float(u & 0xffff0000u));
}
__device__ __forceinline__ unsigned pk2(float x, float y) {
  bf16 bx = __float2bfloat16(x), by = __float2bfloat16(y);
  unsigned short ux, uy;
  __builtin_memcpy(&ux, &bx, 2);
  __builtin_memcpy(&uy, &by, 2);
  return (unsigned)ux | ((unsigned)uy << 16);
}

struct EdgeParams {
  const int* e[6];
  int E[6];
  int ebase[6];
  int nbase[6];
};

struct VSrc {
  const float* hf; const bf16* hh;
  const float* skf; const bf16* skh;
  const int* up;
  int nprev, Ch, Cs;
};

__device__ __forceinline__ float vloadf(const VSrc& s, int i, int c) {
  if (s.up) {
    if (c >= s.Ch) return s.skf[(long)i * s.Cs + (c - s.Ch)];
    if (i >= s.nprev) {
      int j = i - s.nprev;
      int u0 = s.up[2 * j], u1 = s.up[2 * j + 1];
      return 0.5f * (s.hf[(long)u0 * s.Ch + c] + s.hf[(long)u1 * s.Ch + c]);
    }
    return s.hf[(long)i * s.Ch + c];
  }
  return s.hf[(long)i * s.Ch + c];
}

__device__ __forceinline__ float2 vloadh2(const VSrc& s, int i, int c2) {
  int c = 2 * c2;
  if (s.up) {
    if (c >= s.Ch) return ldbf2(s.skh + (long)i * s.Cs + (c - s.Ch));
    if (i >= s.nprev) {
      int j = i - s.nprev;
      int u0 = s.up[2 * j], u1 = s.up[2 * j + 1];
      float2 a = ldbf2(s.hh + (long)u0 * s.Ch + c);
      float2 b = ldbf2(s.hh + (long)u1 * s.Ch + c);
      return make_float2(0.5f * (a.x + b.x), 0.5f * (a.y + b.y));
    }
    return ldbf2(s.hh + (long)i * s.Ch + c);
  }
  return ldbf2(s.hh + (long)i * s.Ch + c);
}

__device__ __forceinline__ float2 vloadf2(const VSrc& s, int i, int c) {
  return make_float2(vloadf(s, i, c), vloadf(s, i, c + 1));
}

// ---------------- setup kernels ----------------
__global__ void k_fill(EdgeParams p, int* __restrict__ cnt, int2* __restrict__ ell, int ET) {
  for (int idx = blockIdx.x * blockDim.x + threadIdx.x; idx < ET; idx += gridDim.x * blockDim.x) {
    int l;
    if (idx < p.ebase[1]) l = 0;
    else if (idx < p.ebase[2]) l = 1;
    else if (idx < p.ebase[3]) l = 2;
    else if (idx < p.ebase[4]) l = 3;
    else if (idx < p.ebase[5]) l = 4;
    else l = 5;
    int e = idx - p.ebase[l];
    const int* epp = p.e[l];
    int row = epp[e];
    int col = epp[p.E[l] + e];
    int g = p.nbase[l] + row;
    int slot = atomicAdd(&cnt[g], 1);
    if (slot < MAXD) ell[g * MAXD + slot].x = col;
  }
}

__global__ void k_wfill(EdgeParams p, const int* __restrict__ cnt, int2* __restrict__ ell, int NT) {
  int total = NT * MAXD;
  for (int idx = blockIdx.x * blockDim.x + threadIdx.x; idx < total; idx += gridDim.x * blockDim.x) {
    int g = idx >> 5;
    int t = idx & (MAXD - 1);
    int dg = cnt[g];
    int d = dg < MAXD ? dg : MAXD;
    if (t < d) {
      int l;
      if (g < p.nbase[1]) l = 0;
      else if (g < p.nbase[2]) l = 1;
      else if (g < p.nbase[3]) l = 2;
      else if (g < p.nbase[4]) l = 3;
      else if (g < p.nbase[5]) l = 4;
      else l = 5;
      int c = ell[idx].x;
      int dc = cnt[p.nbase[l] + c];
      float w = (dc > 0) ? -(rsqrtf((float)dg) * rsqrtf((float)dc)) : 0.0f;
      ell[idx].y = __float_as_int(w);
    }
  }
}

// Merged setup: zero cnt + repack W[3][Cin][Cout] -> Wp[3][Cin/4][Cout][4] + x0 fp32->bf16.
struct WPack {
  const float* src[11];
  float* dst[11];
  int cin[11], cout[11], tot[11];
  const float* x0;
  bf16* x0h;
  int nx0;
};
__global__ void k_setup(WPack P, int TOT, int* __restrict__ cnt, int NT) {
  int TALL = NT + TOT + P.nx0;
  for (int idx = blockIdx.x * blockDim.x + threadIdx.x; idx < TALL; idx += gridDim.x * blockDim.x) {
    if (idx < NT) { cnt[idx] = 0; continue; }
    int off0 = idx - NT;
    if (off0 >= TOT) {
      int j = off0 - TOT;
      P.x0h[j] = __float2bfloat16(P.x0[j]);
      continue;
    }
    int l = 0, off = off0;
    while (off >= P.tot[l]) { off -= P.tot[l]; ++l; }
    int cout = P.cout[l];
    int cinco = P.cin[l] * cout;
    int t = off / cinco;
    int rem = off - t * cinco;
    int k = rem / cout;
    int o = rem - k * cout;
    P.dst[l][((t * (P.cin[l] >> 2) + (k >> 2)) * cout + o) * 4 + (k & 3)] = P.src[l][off];
  }
}

// Materialize virtual upcat source into bf16 flat array.
__global__ void k_xmat(VSrc src, bf16* __restrict__ Xh, int n, int Ctot) {
  int C2 = Ctot >> 1;
  int total = n * C2;
  for (int idx = blockIdx.x * blockDim.x + threadIdx.x; idx < total; idx += gridDim.x * blockDim.x) {
    int i = idx / C2;
    int c2 = idx - i * C2;
    float2 v = vloadf2(src, i, 2 * c2);
    *(unsigned*)(Xh + (long)i * Ctot + 2 * c2) = pk2(v.x, v.y);
  }
}

// ---------------- big-layer t1 gather (2 rows/thread) ----------------
// Gather index clamped to 0 past the row's degree — slot 0 of a degree-0 row is
// uninitialized (0xAA poison -> faulting address otherwise).
__global__ void k_prop_flat(const bf16* __restrict__ Xh, bf16* __restrict__ Th,
                            const int* __restrict__ cnt, const int2* __restrict__ ell,
                            int nbase, int n, int C) {
  int C4 = C >> 2;
  int total = (n >> 1) * C4;  // n even for all big layers
  for (int idx = blockIdx.x * blockDim.x + threadIdx.x; idx < total; idx += gridDim.x * blockDim.x) {
    int ip = idx / C4;
    int c = (idx - ip * C4) << 2;
    int i0 = ip << 1, i1 = i0 + 1;
    int g0 = nbase + i0, g1 = nbase + i1;
    int d0 = cnt[g0]; if (d0 > MAXD) d0 = MAXD;
    int d1 = cnt[g1]; if (d1 > MAXD) d1 = MAXD;
    const int2* cols0 = ell + (long)g0 * MAXD;
    const int2* cols1 = ell + (long)g1 * MAXD;
    float a0 = 0.f, a1 = 0.f, a2 = 0.f, a3 = 0.f;
    float b0 = 0.f, b1 = 0.f, b2 = 0.f, b3 = 0.f;
    int dm = d0 > d1 ? d0 : d1;
    for (int t = 0; t < dm; t += 8) {
      int ciA[8], ciB[8]; float wA[8], wB[8];
#pragma unroll
      for (int j = 0; j < 8; ++j) {
        int tt = t + j;
        int2 eA = cols0[(tt < d0) ? tt : 0];
        int2 eB = cols1[(tt < d1) ? tt : 0];
        ciA[j] = (tt < d0) ? eA.x : 0;
        wA[j] = (tt < d0) ? __int_as_float(eA.y) : 0.f;
        ciB[j] = (tt < d1) ? eB.x : 0;
        wB[j] = (tt < d1) ? __int_as_float(eB.y) : 0.f;
      }
#pragma unroll
      for (int j = 0; j < 8; ++j) {
        uint2 rA = *(const uint2*)(Xh + (long)ciA[j] * C + c);
        uint2 rB = *(const uint2*)(Xh + (long)ciB[j] * C + c);
        float2 vA01 = unpk(rA.x), vA23 = unpk(rA.y);
        float2 vB01 = unpk(rB.x), vB23 = unpk(rB.y);
        a0 += wA[j] * vA01.x; a1 += wA[j] * vA01.y; a2 += wA[j] * vA23.x; a3 += wA[j] * vA23.y;
        b0 += wB[j] * vB01.x; b1 += wB[j] * vB01.y; b2 += wB[j] * vB23.x; b3 += wB[j] * vB23.y;
      }
    }
    long o0 = (long)i0 * C + c;
    long o1 = (long)i1 * C + c;
    uint2 pA; pA.x = pk2(a0, a1); pA.y = pk2(a2, a3);
    uint2 pB; pB.x = pk2(b0, b1); pB.y = pk2(b2, b3);
    *(uint2*)(Th + o0) = pA;
    *(uint2*)(Th + o1) = pB;
  }
}

// mid-layer t1 gather from virtual source; pair of channels/thread.
__global__ void k_prop_v(VSrc src, float* __restrict__ T, bf16* __restrict__ Th,
                         const int* __restrict__ cnt, const int2* __restrict__ ell,
                         int nbase, int n, int C) {
  int C2 = C >> 1;
  int total = n * C2;
  for (int idx = blockIdx.x * blockDim.x + threadIdx.x; idx < total; idx += gridDim.x * blockDim.x) {
    int i = idx / C2;
    int c2 = idx - i * C2;
    int g = nbase + i;
    int d = cnt[g]; if (d > MAXD) d = MAXD;
    const int2* cols = ell + (long)g * MAXD;
    float ax = 0.f, ay = 0.f;
    for (int t = 0; t < d; t += 8) {
      int ci[8]; float wj[8];
#pragma unroll
      for (int j = 0; j < 8; ++j) {
        int tt = t + j;
        int2 e = cols[(tt < d) ? tt : 0];
        ci[j] = e.x;
        wj[j] = (tt < d) ? __int_as_float(e.y) : 0.f;
      }
#pragma unroll
      for (int j = 0; j < 8; ++j) {
        float2 v = vloadh2(src, ci[j], c2);
        ax += wj[j] * v.x;
        ay += wj[j] * v.y;
      }
    }
    long o = (long)i * C + 2 * c2;
    ((float2*)T)[o >> 1] = make_float2(ax, ay);
    *(unsigned*)(Th + o) = pk2(ax, ay);
  }
}

// ---------------- big-layer combine: X/t1 bf16 streams, t2 gathered inline ----------------
// colTiles == 1 for every big layer (Cout <= 64), so the inline t2 gather is
// never duplicated across column tiles. Eliminates the k_prop2 dispatch + t2h
// round-trip; t2 enters the GEMM in fp32. 16 rows/block (RPW=4).
template <int SMAX>
__global__ __launch_bounds__(256) void k_combine_big(
    const bf16* __restrict__ Xh, const bf16* __restrict__ T1h,
    const float4* __restrict__ Wp, const float* __restrict__ B,
    const int* __restrict__ cnt, const int2* __restrict__ ell,
    int nbase, int n, int Cin, int Cout,
    float* __restrict__ OUT, bf16* __restrict__ OUTh) {
  constexpr int RPW = 4;  // 16 rows/block, 4 waves x 4 rows
  __shared__ __align__(16) float sx[4][RPW][64];
  __shared__ __align__(16) float st1[4][RPW][64];
  __shared__ __align__(16) float st2[4][RPW][64];

  int tid = threadIdx.x;
  int w = tid >> 6;
  int lane = tid & 63;

  int colTiles = (Cout + 63) >> 6;
  int ct = blockIdx.x % colTiles;
  int rt = blockIdx.x / colTiles;
  int r0 = rt * (4 * RPW) + w * RPW;
  int o = ct * 64 + lane;
  int oc = (o < Cout) ? o : (Cout - 1);
  int nch = (Cin + 63) >> 6;
  int KQ = Cin >> 2;

  float acc[RPW];
#pragma unroll
  for (int r = 0; r < RPW; ++r) acc[r] = 0.f;

  for (int c = 0; c < nch; ++c) {
    int k0 = c * 64;
    int kw = (Cin - k0 < 64) ? (Cin - k0) : 64;
    int k = k0 + lane;
    bool kv = lane < kw;

#pragma unroll
    for (int rr = 0; rr < RPW; ++rr) {
      int i = r0 + rr;
      bool iv = i < n;
      float xv = 0.f, tv = 0.f, t2v = 0.f;
      if (kv && iv) {
        long off = (long)i * Cin + k;
        xv = bf2f(Xh[off]);
        tv = bf2f(T1h[off]);
        // inline t2 = 2*(A t1) - x, gathered along the coalesced k-lane
        int g = nbase + i;
        int d = cnt[g]; if (d > MAXD) d = MAXD;
        const int2* cols = ell + (long)g * MAXD;
        float a2 = 0.f;
        for (int t = 0; t < d; t += 8) {
          int ci[8]; float wj[8];
#pragma unroll
          for (int j = 0; j < 8; ++j) {
            int tt = t + j;
            int2 e = cols[(tt < d) ? tt : 0];
            ci[j] = e.x;
            wj[j] = (tt < d) ? __int_as_float(e.y) : 0.f;
          }
#pragma unroll
          for (int j = 0; j < 8; ++j)
            a2 += wj[j] * bf2f(T1h[(long)ci[j] * Cin + k]);
        }
        t2v = 2.f * a2 - xv;
      }
      sx[w][rr][lane] = xv;
      st1[w][rr][lane] = tv;
      st2[w][rr][lane] = t2v;
    }
    __syncthreads();

    int kw4 = kw >> 2;
    for (int q = 0; q < kw4; ++q) {
      int kq = (k0 >> 2) + q;
      float4 w0 = Wp[(0 * KQ + kq) * Cout + oc];
      float4 w1 = Wp[(1 * KQ + kq) * Cout + oc];
      float4 w2 = Wp[(2 * KQ + kq) * Cout + oc];
#pragma unroll
      for (int rr = 0; rr < RPW; ++rr) {
        float4 xs = ((const float4*)sx[w][rr])[q];
        float4 t1s = ((const float4*)st1[w][rr])[q];
        float4 t2s = ((const float4*)st2[w][rr])[q];
        acc[rr] += w0.x * xs.x + w0.y * xs.y + w0.z * xs.z + w0.w * xs.w;
        acc[rr] += w1.x * t1s.x + w1.y * t1s.y + w1.z * t1s.z + w1.w * t1s.w;
        acc[rr] += w2.x * t2s.x + w2.y * t2s.y + w2.z * t2s.z + w2.w * t2s.w;
      }
    }
    __syncthreads();
  }

  if constexpr (SMAX) {
    float bb = (o < Cout) ? B[o] : 0.f;
#pragma unroll
    for (int rr = 0; rr < RPW; ++rr) {
      int i = r0 + rr;
      if (i < n) {
        float v = (o < Cout) ? (acc[rr] + bb) : -1e30f;
        float m = v;
        for (int s = 32; s > 0; s >>= 1) m = fmaxf(m, __shfl_xor(m, s));
        float e = (o < Cout) ? __expf(v - m) : 0.f;
        float sum = e;
        for (int s = 32; s > 0; s >>= 1) sum += __shfl_xor(sum, s);
        if (o < Cout) OUT[(long)i * Cout + o] = e / sum;
      }
    }
  } else {
    if (o < Cout) {
      float bb = B[oc];
#pragma unroll
      for (int rr = 0; rr < RPW; ++rr) {
        int i = r0 + rr;
        if (i < n) {
          float v = fmaxf(acc[rr] + bb, 0.f);
          long off = (long)i * Cout + o;
          OUT[off] = v;
          OUTh[off] = __float2bfloat16(v);
        }
      }
    }
  }
}

// ---------------- mid-layer combine: [X|t1|t2] @ Wp + b (+relu), t2 gathered ----------------
// Latency-bound: tile for max blocks + short per-wave chains (round-1 lesson:
// ROWS=8/CW=1 collapsed parallelism and spilled the W preload -> 120us).
template <int ROWS, int CW>
__global__ __launch_bounds__(256) void k_combine(
    VSrc src, const float* __restrict__ T1, const bf16* __restrict__ T1h,
    const float4* __restrict__ Wp, const float* __restrict__ B,
    const int* __restrict__ cnt, const int2* __restrict__ ell,
    int nbase, int n, int Cin, int Cout,
    float* __restrict__ OUT, bf16* __restrict__ OUTh) {
  constexpr int RW = 4 / CW;
  constexpr int RPW = (ROWS * CW) / 4;
  static_assert(RPW * RW == ROWS, "bad ROWS/CW combo");

  __shared__ __align__(16) float sx[4][RPW][64];
  __shared__ __align__(16) float st1[4][RPW][64];
  __shared__ __align__(16) float st2[4][RPW][64];

  int tid = threadIdx.x;
  int w = tid >> 6;
  int lane = tid & 63;
  int rg = w / CW;
  int cw = w % CW;

  int colTiles = (Cout + 63) >> 6;
  int ct = blockIdx.x % colTiles;
  int rt = blockIdx.x / colTiles;
  int r0 = rt * ROWS + rg * RPW;
  int o = ct * 64 + lane;
  int oc = (o < Cout) ? o : (Cout - 1);
  int nch = (Cin + 63) >> 6;
  int KQ = Cin >> 2;

  float acc[RPW];
#pragma unroll
  for (int r = 0; r < RPW; ++r) acc[r] = 0.f;

  for (int cg = 0; cg < nch; cg += CW) {
    int c = cg + cw;
    bool act = c < nch;
    int k0 = c * 64;
    int kw = act ? ((Cin - k0 < 64) ? (Cin - k0) : 64) : 0;
    int k = k0 + lane;
    bool kv = act && (lane < kw);

#pragma unroll
    for (int rr = 0; rr < RPW; ++rr) {
      int i = r0 + rr;
      bool iv = i < n;
      float xv = 0.f, tv = 0.f, t2v = 0.f;
      if (kv && iv) {
        xv = vloadf(src, i, k);
        tv = T1[(long)i * Cin + k];
        int g = nbase + i;
        int d = cnt[g]; if (d > MAXD) d = MAXD;
        const int2* cols = ell + (long)g * MAXD;
        float a2 = 0.f;
        for (int t = 0; t < d; t += 8) {
          int ci[8]; float wj[8];
#pragma unroll
          for (int j = 0; j < 8; ++j) {
            int tt = t + j;
            int2 e = cols[(tt < d) ? tt : 0];
            ci[j] = e.x;
            wj[j] = (tt < d) ? __int_as_float(e.y) : 0.f;
          }
#pragma unroll
          for (int j = 0; j < 8; ++j)
            a2 += wj[j] * bf2f(T1h[(long)ci[j] * Cin + k]);
        }
        t2v = 2.f * a2 - xv;
      }
      sx[w][rr][lane] = xv;
      st1[w][rr][lane] = tv;
      st2[w][rr][lane] = t2v;
    }
    __syncthreads();

    int kw4 = kw >> 2;
    int kqb = k0 >> 2;
    int qb = 0;
    // 8-deep W preload (mid W is L2-cold)
    for (; qb + 8 <= kw4; qb += 8) {
      float4 wb0[8], wb1[8], wb2[8];
#pragma unroll
      for (int q = 0; q < 8; ++q) {
        int kq = kqb + qb + q;
        wb0[q] = Wp[(0 * KQ + kq) * Cout + oc];
        wb1[q] = Wp[(1 * KQ + kq) * Cout + oc];
        wb2[q] = Wp[(2 * KQ + kq) * Cout + oc];
      }
#pragma unroll
      for (int q = 0; q < 8; ++q) {
#pragma unroll
        for (int rr = 0; rr < RPW; ++rr) {
          float4 xs = ((const float4*)sx[w][rr])[qb + q];
          float4 t1s = ((const float4*)st1[w][rr])[qb + q];
          float4 t2s = ((const float4*)st2[w][rr])[qb + q];
          acc[rr] += wb0[q].x * xs.x + wb0[q].y * xs.y + wb0[q].z * xs.z + wb0[q].w * xs.w;
          acc[rr] += wb1[q].x * t1s.x + wb1[q].y * t1s.y + wb1[q].z * t1s.z + wb1[q].w * t1s.w;
          acc[rr] += wb2[q].x * t2s.x + wb2[q].y * t2s.y + wb2[q].z * t2s.z + wb2[q].w * t2s.w;
        }
      }
    }
    for (int q = qb; q < kw4; ++q) {
      int kq = kqb + q;
      float4 w0 = Wp[(0 * KQ + kq) * Cout + oc];
      float4 w1 = Wp[(1 * KQ + kq) * Cout + oc];
      float4 w2 = Wp[(2 * KQ + kq) * Cout + oc];
#pragma unroll
      for (int rr = 0; rr < RPW; ++rr) {
        float4 xs = ((const float4*)sx[w][rr])[q];
        float4 t1s = ((const float4*)st1[w][rr])[q];
        float4 t2s = ((const float4*)st2[w][rr])[q];
        acc[rr] += w0.x * xs.x + w0.y * xs.y + w0.z * xs.z + w0.w * xs.w;
        acc[rr] += w1.x * t1s.x + w1.y * t1s.y + w1.z * t1s.z + w1.w * t1s.w;
        acc[rr] += w2.x * t2s.x + w2.y * t2s.y + w2.z * t2s.z + w2.w * t2s.w;
      }
    }
    __syncthreads();
  }

  if constexpr (CW == 1) {
    if (o < Cout) {
      float bb = B[oc];
#pragma unroll
      for (int rr = 0; rr < RPW; ++rr) {
        int i = r0 + rr;
        if (i < n) {
          float v = fmaxf(acc[rr] + bb, 0.f);
          long off = (long)i * Cout + o;
          OUT[off] = v;
          OUTh[off] = __float2bfloat16(v);
        }
      }
    }
  } else {
#pragma unroll
    for (int rr = 0; rr < RPW; ++rr) sx[w][rr][lane] = acc[rr];
    __syncthreads();
    if (cw == 0 && o < Cout) {
      float bb = B[oc];
#pragma unroll
      for (int rr = 0; rr < RPW; ++rr) {
        int i = r0 + rr;
        if (i < n) {
          float v = bb;
#pragma unroll
          for (int j = 0; j < CW; ++j) v += sx[rg * CW + j][rr][lane];
          v = fmaxf(v, 0.f);
          long off = (long)i * Cout + o;
          OUT[off] = v;
          OUTh[off] = __float2bfloat16(v);
        }
      }
    }
  }
}

// ---------------- launcher ----------------
extern "C" void kernel_launch(void* const* d_in, const int* in_sizes, int n_in,
                              void* d_out, int out_size, void* d_ws, size_t ws_size,
                              hipStream_t stream) {
  static const int NV[6] = {42, 162, 642, 2562, 10242, 40962};
  static const int NE[6] = {240, 960, 3840, 15360, 61440, 245760};
  const int NT = 54612;
  const int ET = 327600;

  EdgeParams ep;
  {
    int nb = 0, eb = 0;
    for (int l = 0; l < 6; ++l) {
      ep.e[l] = (const int*)d_in[1 + l];
      ep.E[l] = NE[l];
      ep.ebase[l] = eb;
      ep.nbase[l] = nb;
      eb += NE[l];
      nb += NV[l];
    }
  }
  const float* x0f = (const float*)d_in[0];
  const int* up[5];
  for (int i = 0; i < 5; ++i) up[i] = (const int*)d_in[7 + i];  // up2..up6
  const float *W[11], *Bb[11];
  for (int i = 0; i < 11; ++i) {
    W[i] = (const float*)d_in[12 + 2 * i];
    Bb[i] = (const float*)d_in[13 + 2 * i];
  }
  static const int LCI[11] = {4, 32, 64, 128, 256, 512, 768, 384, 192, 96, 36};
  static const int LCO[11] = {32, 64, 128, 256, 512, 512, 256, 128, 64, 32, 37};

  // ---- workspace carve (16B-aligned) ----
  char* p = (char*)d_ws;
  auto alloc_b = [&](size_t bytes) { void* r = (void*)p; p += (bytes + 15) & ~size_t(15); return r; };
  auto alloc_i = [&](size_t ne) { return (int*)alloc_b(ne * 4); };
  auto alloc_f = [&](size_t ne) { return (float*)alloc_b(ne * 4); };
  auto alloc_h = [&](size_t ne) { return (bf16*)alloc_b(ne * 2); };
  int* cnt = alloc_i(NT);
  int2* ell = (int2*)alloc_b((size_t)NT * MAXD * 8);
  float* t1f = alloc_f((size_t)40962 * 36);   // mid-layer fp32 t1
  bf16* t1h = alloc_h((size_t)40962 * 36);
  bf16* x0h = alloc_h((size_t)40962 * 4);
  bf16* xh = alloc_h((size_t)40962 * 36);     // L10/L11 materialized bf16 X
  float* wp[11];
  for (int i = 0; i < 11; ++i) wp[i] = alloc_f((size_t)3 * LCI[i] * LCO[i]);
  float *af[10]; bf16 *ah[10];
  const int an[10] = {40962, 10242, 2562, 642, 162, 42, 162, 642, 2562, 10242};
  const int ac[10] = {32, 64, 128, 256, 512, 512, 256, 128, 64, 32};
  for (int i = 0; i < 10; ++i) {
    af[i] = alloc_f((size_t)an[i] * ac[i]);
    ah[i] = alloc_h((size_t)an[i] * ac[i]);
  }

  {
    WPack P;
    int TOT = 0;
    for (int i = 0; i < 11; ++i) {
      P.src[i] = W[i];
      P.dst[i] = wp[i];
      P.cin[i] = LCI[i];
      P.cout[i] = LCO[i];
      P.tot[i] = 3 * LCI[i] * LCO[i];
      TOT += P.tot[i];
    }
    P.x0 = x0f; P.x0h = x0h; P.nx0 = 40962 * 4;
    k_setup<<<(NT + TOT + P.nx0 + 255) / 256, 256, 0, stream>>>(P, TOT, cnt, NT);
  }
  k_fill<<<(ET + 255) / 256, 256, 0, stream>>>(ep, cnt, ell, ET);
  k_wfill<<<(NT * MAXD + 255) / 256, 256, 0, stream>>>(ep, cnt, ell, NT);

  auto plain = [](const float* hf, const bf16* hh, int Ch) {
    VSrc s{hf, hh, nullptr, nullptr, nullptr, 0, Ch, 0}; return s;
  };
  auto upsrc = [](const float* hf, const bf16* hh, const float* skf, const bf16* skh,
                  const int* u, int nprev, int Ch, int Cs) {
    VSrc s{hf, hh, skf, skh, u, nprev, Ch, Cs}; return s;
  };

  // big layer: t1 gather + combine with inline t2 gather (prop2 eliminated)
  auto big = [&](const bf16* Xh, float* OUT, bf16* OUTh, int lvl, int n,
                 int Cin, int Cout, const float* Wq, const float* Bp, int smax) {
    int nb = ep.nbase[lvl];
    int t4p = (n >> 1) * (Cin >> 2);
    k_prop_flat<<<(t4p + 255) / 256, 256, 0, stream>>>(Xh, t1h, cnt, ell, nb, n, Cin);
    int grid = ((Cout + 63) / 64) * ((n + 15) / 16);
    if (smax)
      k_combine_big<1><<<grid, 256, 0, stream>>>(Xh, t1h, (const float4*)Wq, Bp, cnt, ell, nb, n, Cin, Cout, OUT, OUTh);
    else
      k_combine_big<0><<<grid, 256, 0, stream>>>(Xh, t1h, (const float4*)Wq, Bp, cnt, ell, nb, n, Cin, Cout, OUT, OUTh);
  };

  // mid layer: virtual prop + gather-combine with W batching (proven 517us tilings)
#define MID(RS, CWv, s, OUT, OUTh, lvl, n, Cin, Cout, Wq, Bp)                                   \
  {                                                                                             \
    int nb = ep.nbase[lvl];                                                                     \
    int t2n = (n) * ((Cin) >> 1);                                                               \
    k_prop_v<<<(t2n + 255) / 256, 256, 0, stream>>>(s, t1f, t1h, cnt, ell, nb, n, Cin);         \
    int grid = (((Cout) + 63) / 64) * (((n) + (RS)-1) / (RS));                                  \
    k_combine<RS, CWv><<<grid, 256, 0, stream>>>(s, t1f, t1h, (const float4*)Wq,                \
                                                 Bp, cnt, ell, nb, n, Cin, Cout, OUT, OUTh);    \
  }

  // ---- L1: n=40962, 4->32 ----
  big(x0h, af[0], ah[0], 5, 40962, 4, 32, wp[0], Bb[0], 0);
  // ---- L2: n=10242, 32->64 ----
  big(ah[0], af[1], ah[1], 4, 10242, 32, 64, wp[1], Bb[1], 0);
  // ---- mid encoder ----
  MID(4, 1, plain(af[1], ah[1], 64), af[2], ah[2], 3, 2562, 64, 128, wp[2], Bb[2]);
  MID(2, 2, plain(af[2], ah[2], 128), af[3], ah[3], 2, 642, 128, 256, wp[3], Bb[3]);
  MID(1, 4, plain(af[3], ah[3], 256), af[4], ah[4], 1, 162, 256, 512, wp[4], Bb[4]);
  MID(1, 4, plain(af[4], ah[4], 512), af[5], ah[5], 0, 42, 512, 512, wp[5], Bb[5]);
  // ---- mid decoder ----
  MID(1, 4, upsrc(af[5], ah[5], af[3], ah[3], up[0], 42, 512, 256), af[6], ah[6], 1, 162, 768, 256, wp[6], Bb[6]);
  MID(2, 4, upsrc(af[6], ah[6], af[2], ah[2], up[1], 162, 256, 128), af[7], ah[7], 2, 642, 384, 128, wp[7], Bb[7]);
  MID(2, 4, upsrc(af[7], ah[7], af[1], ah[1], up[2], 642, 128, 64), af[8], ah[8], 3, 2562, 192, 64, wp[8], Bb[8]);
  // ---- L10: n=10242, [64|32]->32 ----
  {
    VSrc s = upsrc(af[8], ah[8], af[0], ah[0], up[3], 2562, 64, 32);
    k_xmat<<<(10242 * 48 + 255) / 256, 256, 0, stream>>>(s, xh, 10242, 96);
    big(xh, af[9], ah[9], 4, 10242, 96, 32, wp[9], Bb[9], 0);
  }
  // ---- L11: n=40962, [32|4]->37 + softmax ----
  {
    VSrc s = upsrc(af[9], ah[9], x0f, x0h, up[4], 10242, 32, 4);
    k_xmat<<<(40962 * 18 + 255) / 256, 256, 0, stream>>>(s, xh, 40962, 36);
    big(xh, (float*)d_out, nullptr, 5, 40962, 36, 37, wp[10], Bb[10], 1);
  }
}

// Round 6
// 490.913 us; speedup vs baseline: 4.4349x; 1.0635x over previous
//
#include <hip/hip_runtime.h>
#include <hip/hip_bf16.h>

#define MAXD 32
typedef __hip_bfloat16 bf16;

__device__ __forceinline__ float bf2f(bf16 v) { return __bfloat162float(v); }
__device__ __forceinline__ float2 ldbf2(const bf16* p) {
  unsigned u = *(const unsigned*)p;
  return make_float2(__uint_as_float(u << 16), __uint_as_float(u & 0xffff0000u));
}
__device__ __forceinline__ float2 unpk(unsigned u) {
  return make_float2(__uint_as_float(u << 16), __uint_as_float(u & 0xffff0000u));
}
__device__ __forceinline__ unsigned pk2(float x, float y) {
  bf16 bx = __float2bfloat16(x), by = __float2bfloat16(y);
  unsigned short ux, uy;
  __builtin_memcpy(&ux, &bx, 2);
  __builtin_memcpy(&uy, &by, 2);
  return (unsigned)ux | ((unsigned)uy << 16);
}

struct EdgeParams {
  const int* e[6];
  int E[6];
  int ebase[6];
  int nbase[6];
};

struct VSrc {
  const float* hf; const bf16* hh;
  const float* skf; const bf16* skh;
  const int* up;
  int nprev, Ch, Cs;
};

__device__ __forceinline__ float vloadf(const VSrc& s, int i, int c) {
  if (s.up) {
    if (c >= s.Ch) return s.skf[(long)i * s.Cs + (c - s.Ch)];
    if (i >= s.nprev) {
      int j = i - s.nprev;
      int u0 = s.up[2 * j], u1 = s.up[2 * j + 1];
      return 0.5f * (s.hf[(long)u0 * s.Ch + c] + s.hf[(long)u1 * s.Ch + c]);
    }
    return s.hf[(long)i * s.Ch + c];
  }
  return s.hf[(long)i * s.Ch + c];
}

__device__ __forceinline__ float2 vloadh2(const VSrc& s, int i, int c2) {
  int c = 2 * c2;
  if (s.up) {
    if (c >= s.Ch) return ldbf2(s.skh + (long)i * s.Cs + (c - s.Ch));
    if (i >= s.nprev) {
      int j = i - s.nprev;
      int u0 = s.up[2 * j], u1 = s.up[2 * j + 1];
      float2 a = ldbf2(s.hh + (long)u0 * s.Ch + c);
      float2 b = ldbf2(s.hh + (long)u1 * s.Ch + c);
      return make_float2(0.5f * (a.x + b.x), 0.5f * (a.y + b.y));
    }
    return ldbf2(s.hh + (long)i * s.Ch + c);
  }
  return ldbf2(s.hh + (long)i * s.Ch + c);
}

__device__ __forceinline__ float2 vloadf2(const VSrc& s, int i, int c) {
  return make_float2(vloadf(s, i, c), vloadf(s, i, c + 1));
}

// ---------------- setup kernels ----------------
__global__ void k_fill(EdgeParams p, int* __restrict__ cnt, int2* __restrict__ ell, int ET) {
  for (int idx = blockIdx.x * blockDim.x + threadIdx.x; idx < ET; idx += gridDim.x * blockDim.x) {
    int l;
    if (idx < p.ebase[1]) l = 0;
    else if (idx < p.ebase[2]) l = 1;
    else if (idx < p.ebase[3]) l = 2;
    else if (idx < p.ebase[4]) l = 3;
    else if (idx < p.ebase[5]) l = 4;
    else l = 5;
    int e = idx - p.ebase[l];
    const int* epp = p.e[l];
    int row = epp[e];
    int col = epp[p.E[l] + e];
    int g = p.nbase[l] + row;
    int slot = atomicAdd(&cnt[g], 1);
    if (slot < MAXD) ell[g * MAXD + slot].x = col;
  }
}

__global__ void k_wfill(EdgeParams p, const int* __restrict__ cnt, int2* __restrict__ ell, int NT) {
  int total = NT * MAXD;
  for (int idx = blockIdx.x * blockDim.x + threadIdx.x; idx < total; idx += gridDim.x * blockDim.x) {
    int g = idx >> 5;
    int t = idx & (MAXD - 1);
    int dg = cnt[g];
    int d = dg < MAXD ? dg : MAXD;
    if (t < d) {
      int l;
      if (g < p.nbase[1]) l = 0;
      else if (g < p.nbase[2]) l = 1;
      else if (g < p.nbase[3]) l = 2;
      else if (g < p.nbase[4]) l = 3;
      else if (g < p.nbase[5]) l = 4;
      else l = 5;
      int c = ell[idx].x;
      int dc = cnt[p.nbase[l] + c];
      float w = (dc > 0) ? -(rsqrtf((float)dg) * rsqrtf((float)dc)) : 0.0f;
      ell[idx].y = __float_as_int(w);
    }
  }
}

// Merged setup: zero cnt + repack W[3][Cin][Cout] -> Wp[3][Cin/4][Cout][4] + x0 fp32->bf16.
struct WPack {
  const float* src[11];
  float* dst[11];
  int cin[11], cout[11], tot[11];
  const float* x0;
  bf16* x0h;
  int nx0;
};
__global__ void k_setup(WPack P, int TOT, int* __restrict__ cnt, int NT) {
  int TALL = NT + TOT + P.nx0;
  for (int idx = blockIdx.x * blockDim.x + threadIdx.x; idx < TALL; idx += gridDim.x * blockDim.x) {
    if (idx < NT) { cnt[idx] = 0; continue; }
    int off0 = idx - NT;
    if (off0 >= TOT) {
      int j = off0 - TOT;
      P.x0h[j] = __float2bfloat16(P.x0[j]);
      continue;
    }
    int l = 0, off = off0;
    while (off >= P.tot[l]) { off -= P.tot[l]; ++l; }
    int cout = P.cout[l];
    int cinco = P.cin[l] * cout;
    int t = off / cinco;
    int rem = off - t * cinco;
    int k = rem / cout;
    int o = rem - k * cout;
    P.dst[l][((t * (P.cin[l] >> 2) + (k >> 2)) * cout + o) * 4 + (k & 3)] = P.src[l][off];
  }
}

// Materialize virtual upcat source into bf16 flat array.
__global__ void k_xmat(VSrc src, bf16* __restrict__ Xh, int n, int Ctot) {
  int C2 = Ctot >> 1;
  int total = n * C2;
  for (int idx = blockIdx.x * blockDim.x + threadIdx.x; idx < total; idx += gridDim.x * blockDim.x) {
    int i = idx / C2;
    int c2 = idx - i * C2;
    float2 v = vloadf2(src, i, 2 * c2);
    *(unsigned*)(Xh + (long)i * Ctot + 2 * c2) = pk2(v.x, v.y);
  }
}

// ---------------- big-layer t1 gather (2 rows/thread) ----------------
// Gather index clamped to 0 past the row's degree — slot 0 of a degree-0 row is
// uninitialized (0xAA poison -> faulting address otherwise).
__global__ void k_prop_flat(const bf16* __restrict__ Xh, bf16* __restrict__ Th,
                            const int* __restrict__ cnt, const int2* __restrict__ ell,
                            int nbase, int n, int C) {
  int C4 = C >> 2;
  int total = (n >> 1) * C4;  // n even for all big layers
  for (int idx = blockIdx.x * blockDim.x + threadIdx.x; idx < total; idx += gridDim.x * blockDim.x) {
    int ip = idx / C4;
    int c = (idx - ip * C4) << 2;
    int i0 = ip << 1, i1 = i0 + 1;
    int g0 = nbase + i0, g1 = nbase + i1;
    int d0 = cnt[g0]; if (d0 > MAXD) d0 = MAXD;
    int d1 = cnt[g1]; if (d1 > MAXD) d1 = MAXD;
    const int2* cols0 = ell + (long)g0 * MAXD;
    const int2* cols1 = ell + (long)g1 * MAXD;
    float a0 = 0.f, a1 = 0.f, a2 = 0.f, a3 = 0.f;
    float b0 = 0.f, b1 = 0.f, b2 = 0.f, b3 = 0.f;
    int dm = d0 > d1 ? d0 : d1;
    for (int t = 0; t < dm; t += 8) {
      int ciA[8], ciB[8]; float wA[8], wB[8];
#pragma unroll
      for (int j = 0; j < 8; ++j) {
        int tt = t + j;
        int2 eA = cols0[(tt < d0) ? tt : 0];
        int2 eB = cols1[(tt < d1) ? tt : 0];
        ciA[j] = (tt < d0) ? eA.x : 0;
        wA[j] = (tt < d0) ? __int_as_float(eA.y) : 0.f;
        ciB[j] = (tt < d1) ? eB.x : 0;
        wB[j] = (tt < d1) ? __int_as_float(eB.y) : 0.f;
      }
#pragma unroll
      for (int j = 0; j < 8; ++j) {
        uint2 rA = *(const uint2*)(Xh + (long)ciA[j] * C + c);
        uint2 rB = *(const uint2*)(Xh + (long)ciB[j] * C + c);
        float2 vA01 = unpk(rA.x), vA23 = unpk(rA.y);
        float2 vB01 = unpk(rB.x), vB23 = unpk(rB.y);
        a0 += wA[j] * vA01.x; a1 += wA[j] * vA01.y; a2 += wA[j] * vA23.x; a3 += wA[j] * vA23.y;
        b0 += wB[j] * vB01.x; b1 += wB[j] * vB01.y; b2 += wB[j] * vB23.x; b3 += wB[j] * vB23.y;
      }
    }
    long o0 = (long)i0 * C + c;
    long o1 = (long)i1 * C + c;
    uint2 pA; pA.x = pk2(a0, a1); pA.y = pk2(a2, a3);
    uint2 pB; pB.x = pk2(b0, b1); pB.y = pk2(b2, b3);
    *(uint2*)(Th + o0) = pA;
    *(uint2*)(Th + o1) = pB;
  }
}

// mid-layer t1 gather from virtual source; pair of channels/thread.
__global__ void k_prop_v(VSrc src, float* __restrict__ T, bf16* __restrict__ Th,
                         const int* __restrict__ cnt, const int2* __restrict__ ell,
                         int nbase, int n, int C) {
  int C2 = C >> 1;
  int total = n * C2;
  for (int idx = blockIdx.x * blockDim.x + threadIdx.x; idx < total; idx += gridDim.x * blockDim.x) {
    int i = idx / C2;
    int c2 = idx - i * C2;
    int g = nbase + i;
    int d = cnt[g]; if (d > MAXD) d = MAXD;
    const int2* cols = ell + (long)g * MAXD;
    float ax = 0.f, ay = 0.f;
    for (int t = 0; t < d; t += 8) {
      int ci[8]; float wj[8];
#pragma unroll
      for (int j = 0; j < 8; ++j) {
        int tt = t + j;
        int2 e = cols[(tt < d) ? tt : 0];
        ci[j] = e.x;
        wj[j] = (tt < d) ? __int_as_float(e.y) : 0.f;
      }
#pragma unroll
      for (int j = 0; j < 8; ++j) {
        float2 v = vloadh2(src, ci[j], c2);
        ax += wj[j] * v.x;
        ay += wj[j] * v.y;
      }
    }
    long o = (long)i * C + 2 * c2;
    ((float2*)T)[o >> 1] = make_float2(ax, ay);
    *(unsigned*)(Th + o) = pk2(ax, ay);
  }
}

// ---------------- big-layer combine: X/t1 bf16 streams, t2 gathered inline ----------------
// Channel-vectorized staging (round-5 lesson): sub = lane>>4 picks the row
// (exactly RPW=4), cg = lane&15 picks a 4-channel group. Each thread gathers
// 4 channels via uint2 loads and reads ELL metadata ONCE per row — 1/4 the
// gather loads + 1/4 metadata reads vs per-channel staging, identical math.
// colTiles == 1 for every big layer (Cout <= 64) so the inline t2 gather is
// never duplicated. All big-layer Cin (4,32,36,96) are multiples of 4 ->
// uint2 (8B) row accesses stay aligned.
template <int SMAX>
__global__ __launch_bounds__(256) void k_combine_big(
    const bf16* __restrict__ Xh, const bf16* __restrict__ T1h,
    const float4* __restrict__ Wp, const float* __restrict__ B,
    const int* __restrict__ cnt, const int2* __restrict__ ell,
    int nbase, int n, int Cin, int Cout,
    float* __restrict__ OUT, bf16* __restrict__ OUTh) {
  constexpr int RPW = 4;  // 16 rows/block, 4 waves x 4 rows (sub mapping needs RPW==4)
  __shared__ __align__(16) float sx[4][RPW][64];
  __shared__ __align__(16) float st1[4][RPW][64];
  __shared__ __align__(16) float st2[4][RPW][64];

  int tid = threadIdx.x;
  int w = tid >> 6;
  int lane = tid & 63;

  int colTiles = (Cout + 63) >> 6;
  int ct = blockIdx.x % colTiles;
  int rt = blockIdx.x / colTiles;
  int r0 = rt * (4 * RPW) + w * RPW;
  int o = ct * 64 + lane;
  int oc = (o < Cout) ? o : (Cout - 1);
  int nch = (Cin + 63) >> 6;
  int KQ = Cin >> 2;

  float acc[RPW];
#pragma unroll
  for (int r = 0; r < RPW; ++r) acc[r] = 0.f;

  for (int c = 0; c < nch; ++c) {
    int k0 = c * 64;
    int kw = (Cin - k0 < 64) ? (Cin - k0) : 64;

    // ---- channel-vectorized staging: 1 row x 4 channels per thread ----
    {
      int sub = lane >> 4;        // row within RPW
      int cg = lane & 15;         // float4 group within this 64-ch tile
      int k4 = k0 + (cg << 2);
      int i = r0 + sub;
      float4 xv4 = make_float4(0.f, 0.f, 0.f, 0.f);
      float4 t1v4 = xv4, t2v4 = xv4;
      if (i < n && (cg << 2) < kw) {
        long off = (long)i * Cin + k4;
        uint2 rx = *(const uint2*)(Xh + off);
        float2 xa = unpk(rx.x), xb = unpk(rx.y);
        uint2 rt1 = *(const uint2*)(T1h + off);
        float2 ta = unpk(rt1.x), tb = unpk(rt1.y);
        int g = nbase + i;
        int d = cnt[g]; if (d > MAXD) d = MAXD;
        const int2* cols = ell + (long)g * MAXD;
        float a0 = 0.f, a1 = 0.f, a2 = 0.f, a3 = 0.f;
        for (int t = 0; t < d; t += 8) {
          int ci[8]; float wj[8];
#pragma unroll
          for (int j = 0; j < 8; ++j) {
            int tt = t + j;
            int2 e = cols[(tt < d) ? tt : 0];
            ci[j] = e.x;
            wj[j] = (tt < d) ? __int_as_float(e.y) : 0.f;
          }
#pragma unroll
          for (int j = 0; j < 8; ++j) {
            uint2 r = *(const uint2*)(T1h + (long)ci[j] * Cin + k4);
            float2 va = unpk(r.x), vb = unpk(r.y);
            a0 += wj[j] * va.x; a1 += wj[j] * va.y;
            a2 += wj[j] * vb.x; a3 += wj[j] * vb.y;
          }
        }
        xv4 = make_float4(xa.x, xa.y, xb.x, xb.y);
        t1v4 = make_float4(ta.x, ta.y, tb.x, tb.y);
        t2v4 = make_float4(2.f * a0 - xa.x, 2.f * a1 - xa.y,
                           2.f * a2 - xb.x, 2.f * a3 - xb.y);
      }
      ((float4*)sx[w][sub])[cg] = xv4;
      ((float4*)st1[w][sub])[cg] = t1v4;
      ((float4*)st2[w][sub])[cg] = t2v4;
    }
    __syncthreads();

    int kw4 = kw >> 2;
    for (int q = 0; q < kw4; ++q) {
      int kq = (k0 >> 2) + q;
      float4 w0 = Wp[(0 * KQ + kq) * Cout + oc];
      float4 w1 = Wp[(1 * KQ + kq) * Cout + oc];
      float4 w2 = Wp[(2 * KQ + kq) * Cout + oc];
#pragma unroll
      for (int rr = 0; rr < RPW; ++rr) {
        float4 xs = ((const float4*)sx[w][rr])[q];
        float4 t1s = ((const float4*)st1[w][rr])[q];
        float4 t2s = ((const float4*)st2[w][rr])[q];
        acc[rr] += w0.x * xs.x + w0.y * xs.y + w0.z * xs.z + w0.w * xs.w;
        acc[rr] += w1.x * t1s.x + w1.y * t1s.y + w1.z * t1s.z + w1.w * t1s.w;
        acc[rr] += w2.x * t2s.x + w2.y * t2s.y + w2.z * t2s.z + w2.w * t2s.w;
      }
    }
    __syncthreads();
  }

  if constexpr (SMAX) {
    float bb = (o < Cout) ? B[o] : 0.f;
#pragma unroll
    for (int rr = 0; rr < RPW; ++rr) {
      int i = r0 + rr;
      if (i < n) {
        float v = (o < Cout) ? (acc[rr] + bb) : -1e30f;
        float m = v;
        for (int s = 32; s > 0; s >>= 1) m = fmaxf(m, __shfl_xor(m, s));
        float e = (o < Cout) ? __expf(v - m) : 0.f;
        float sum = e;
        for (int s = 32; s > 0; s >>= 1) sum += __shfl_xor(sum, s);
        if (o < Cout) OUT[(long)i * Cout + o] = e / sum;
      }
    }
  } else {
    if (o < Cout) {
      float bb = B[oc];
#pragma unroll
      for (int rr = 0; rr < RPW; ++rr) {
        int i = r0 + rr;
        if (i < n) {
          float v = fmaxf(acc[rr] + bb, 0.f);
          long off = (long)i * Cout + o;
          OUT[off] = v;
          OUTh[off] = __float2bfloat16(v);
        }
      }
    }
  }
}

// ---------------- mid-layer combine: [X|t1|t2] @ Wp + b (+relu), t2 gathered ----------------
// Latency-bound: tile for max blocks + short per-wave chains (round-1 lesson:
// ROWS=8/CW=1 collapsed parallelism and spilled the W preload -> 120us).
template <int ROWS, int CW>
__global__ __launch_bounds__(256) void k_combine(
    VSrc src, const float* __restrict__ T1, const bf16* __restrict__ T1h,
    const float4* __restrict__ Wp, const float* __restrict__ B,
    const int* __restrict__ cnt, const int2* __restrict__ ell,
    int nbase, int n, int Cin, int Cout,
    float* __restrict__ OUT, bf16* __restrict__ OUTh) {
  constexpr int RW = 4 / CW;
  constexpr int RPW = (ROWS * CW) / 4;
  static_assert(RPW * RW == ROWS, "bad ROWS/CW combo");

  __shared__ __align__(16) float sx[4][RPW][64];
  __shared__ __align__(16) float st1[4][RPW][64];
  __shared__ __align__(16) float st2[4][RPW][64];

  int tid = threadIdx.x;
  int w = tid >> 6;
  int lane = tid & 63;
  int rg = w / CW;
  int cw = w % CW;

  int colTiles = (Cout + 63) >> 6;
  int ct = blockIdx.x % colTiles;
  int rt = blockIdx.x / colTiles;
  int r0 = rt * ROWS + rg * RPW;
  int o = ct * 64 + lane;
  int oc = (o < Cout) ? o : (Cout - 1);
  int nch = (Cin + 63) >> 6;
  int KQ = Cin >> 2;

  float acc[RPW];
#pragma unroll
  for (int r = 0; r < RPW; ++r) acc[r] = 0.f;

  for (int cg = 0; cg < nch; cg += CW) {
    int c = cg + cw;
    bool act = c < nch;
    int k0 = c * 64;
    int kw = act ? ((Cin - k0 < 64) ? (Cin - k0) : 64) : 0;
    int k = k0 + lane;
    bool kv = act && (lane < kw);

#pragma unroll
    for (int rr = 0; rr < RPW; ++rr) {
      int i = r0 + rr;
      bool iv = i < n;
      float xv = 0.f, tv = 0.f, t2v = 0.f;
      if (kv && iv) {
        xv = vloadf(src, i, k);
        tv = T1[(long)i * Cin + k];
        int g = nbase + i;
        int d = cnt[g]; if (d > MAXD) d = MAXD;
        const int2* cols = ell + (long)g * MAXD;
        float a2 = 0.f;
        for (int t = 0; t < d; t += 8) {
          int ci[8]; float wj[8];
#pragma unroll
          for (int j = 0; j < 8; ++j) {
            int tt = t + j;
            int2 e = cols[(tt < d) ? tt : 0];
            ci[j] = e.x;
            wj[j] = (tt < d) ? __int_as_float(e.y) : 0.f;
          }
#pragma unroll
          for (int j = 0; j < 8; ++j)
            a2 += wj[j] * bf2f(T1h[(long)ci[j] * Cin + k]);
        }
        t2v = 2.f * a2 - xv;
      }
      sx[w][rr][lane] = xv;
      st1[w][rr][lane] = tv;
      st2[w][rr][lane] = t2v;
    }
    __syncthreads();

    int kw4 = kw >> 2;
    int kqb = k0 >> 2;
    int qb = 0;
    // 8-deep W preload (mid W is L2-cold)
    for (; qb + 8 <= kw4; qb += 8) {
      float4 wb0[8], wb1[8], wb2[8];
#pragma unroll
      for (int q = 0; q < 8; ++q) {
        int kq = kqb + qb + q;
        wb0[q] = Wp[(0 * KQ + kq) * Cout + oc];
        wb1[q] = Wp[(1 * KQ + kq) * Cout + oc];
        wb2[q] = Wp[(2 * KQ + kq) * Cout + oc];
      }
#pragma unroll
      for (int q = 0; q < 8; ++q) {
#pragma unroll
        for (int rr = 0; rr < RPW; ++rr) {
          float4 xs = ((const float4*)sx[w][rr])[qb + q];
          float4 t1s = ((const float4*)st1[w][rr])[qb + q];
          float4 t2s = ((const float4*)st2[w][rr])[qb + q];
          acc[rr] += wb0[q].x * xs.x + wb0[q].y * xs.y + wb0[q].z * xs.z + wb0[q].w * xs.w;
          acc[rr] += wb1[q].x * t1s.x + wb1[q].y * t1s.y + wb1[q].z * t1s.z + wb1[q].w * t1s.w;
          acc[rr] += wb2[q].x * t2s.x + wb2[q].y * t2s.y + wb2[q].z * t2s.z + wb2[q].w * t2s.w;
        }
      }
    }
    for (int q = qb; q < kw4; ++q) {
      int kq = kqb + q;
      float4 w0 = Wp[(0 * KQ + kq) * Cout + oc];
      float4 w1 = Wp[(1 * KQ + kq) * Cout + oc];
      float4 w2 = Wp[(2 * KQ + kq) * Cout + oc];
#pragma unroll
      for (int rr = 0; rr < RPW; ++rr) {
        float4 xs = ((const float4*)sx[w][rr])[q];
        float4 t1s = ((const float4*)st1[w][rr])[q];
        float4 t2s = ((const float4*)st2[w][rr])[q];
        acc[rr] += w0.x * xs.x + w0.y * xs.y + w0.z * xs.z + w0.w * xs.w;
        acc[rr] += w1.x * t1s.x + w1.y * t1s.y + w1.z * t1s.z + w1.w * t1s.w;
        acc[rr] += w2.x * t2s.x + w2.y * t2s.y + w2.z * t2s.z + w2.w * t2s.w;
      }
    }
    __syncthreads();
  }

  if constexpr (CW == 1) {
    if (o < Cout) {
      float bb = B[oc];
#pragma unroll
      for (int rr = 0; rr < RPW; ++rr) {
        int i = r0 + rr;
        if (i < n) {
          float v = fmaxf(acc[rr] + bb, 0.f);
          long off = (long)i * Cout + o;
          OUT[off] = v;
          OUTh[off] = __float2bfloat16(v);
        }
      }
    }
  } else {
#pragma unroll
    for (int rr = 0; rr < RPW; ++rr) sx[w][rr][lane] = acc[rr];
    __syncthreads();
    if (cw == 0 && o < Cout) {
      float bb = B[oc];
#pragma unroll
      for (int rr = 0; rr < RPW; ++rr) {
        int i = r0 + rr;
        if (i < n) {
          float v = bb;
#pragma unroll
          for (int j = 0; j < CW; ++j) v += sx[rg * CW + j][rr][lane];
          v = fmaxf(v, 0.f);
          long off = (long)i * Cout + o;
          OUT[off] = v;
          OUTh[off] = __float2bfloat16(v);
        }
      }
    }
  }
}

// ---------------- launcher ----------------
extern "C" void kernel_launch(void* const* d_in, const int* in_sizes, int n_in,
                              void* d_out, int out_size, void* d_ws, size_t ws_size,
                              hipStream_t stream) {
  static const int NV[6] = {42, 162, 642, 2562, 10242, 40962};
  static const int NE[6] = {240, 960, 3840, 15360, 61440, 245760};
  const int NT = 54612;
  const int ET = 327600;

  EdgeParams ep;
  {
    int nb = 0, eb = 0;
    for (int l = 0; l < 6; ++l) {
      ep.e[l] = (const int*)d_in[1 + l];
      ep.E[l] = NE[l];
      ep.ebase[l] = eb;
      ep.nbase[l] = nb;
      eb += NE[l];
      nb += NV[l];
    }
  }
  const float* x0f = (const float*)d_in[0];
  const int* up[5];
  for (int i = 0; i < 5; ++i) up[i] = (const int*)d_in[7 + i];  // up2..up6
  const float *W[11], *Bb[11];
  for (int i = 0; i < 11; ++i) {
    W[i] = (const float*)d_in[12 + 2 * i];
    Bb[i] = (const float*)d_in[13 + 2 * i];
  }
  static const int LCI[11] = {4, 32, 64, 128, 256, 512, 768, 384, 192, 96, 36};
  static const int LCO[11] = {32, 64, 128, 256, 512, 512, 256, 128, 64, 32, 37};

  // ---- workspace carve (16B-aligned) ----
  char* p = (char*)d_ws;
  auto alloc_b = [&](size_t bytes) { void* r = (void*)p; p += (bytes + 15) & ~size_t(15); return r; };
  auto alloc_i = [&](size_t ne) { return (int*)alloc_b(ne * 4); };
  auto alloc_f = [&](size_t ne) { return (float*)alloc_b(ne * 4); };
  auto alloc_h = [&](size_t ne) { return (bf16*)alloc_b(ne * 2); };
  int* cnt = alloc_i(NT);
  int2* ell = (int2*)alloc_b((size_t)NT * MAXD * 8);
  float* t1f = alloc_f((size_t)40962 * 36);   // mid-layer fp32 t1
  bf16* t1h = alloc_h((size_t)40962 * 36);
  bf16* x0h = alloc_h((size_t)40962 * 4);
  bf16* xh = alloc_h((size_t)40962 * 36);     // L10/L11 materialized bf16 X
  float* wp[11];
  for (int i = 0; i < 11; ++i) wp[i] = alloc_f((size_t)3 * LCI[i] * LCO[i]);
  float *af[10]; bf16 *ah[10];
  const int an[10] = {40962, 10242, 2562, 642, 162, 42, 162, 642, 2562, 10242};
  const int ac[10] = {32, 64, 128, 256, 512, 512, 256, 128, 64, 32};
  for (int i = 0; i < 10; ++i) {
    af[i] = alloc_f((size_t)an[i] * ac[i]);
    ah[i] = alloc_h((size_t)an[i] * ac[i]);
  }

  {
    WPack P;
    int TOT = 0;
    for (int i = 0; i < 11; ++i) {
      P.src[i] = W[i];
      P.dst[i] = wp[i];
      P.cin[i] = LCI[i];
      P.cout[i] = LCO[i];
      P.tot[i] = 3 * LCI[i] * LCO[i];
      TOT += P.tot[i];
    }
    P.x0 = x0f; P.x0h = x0h; P.nx0 = 40962 * 4;
    k_setup<<<(NT + TOT + P.nx0 + 255) / 256, 256, 0, stream>>>(P, TOT, cnt, NT);
  }
  k_fill<<<(ET + 255) / 256, 256, 0, stream>>>(ep, cnt, ell, ET);
  k_wfill<<<(NT * MAXD + 255) / 256, 256, 0, stream>>>(ep, cnt, ell, NT);

  auto plain = [](const float* hf, const bf16* hh, int Ch) {
    VSrc s{hf, hh, nullptr, nullptr, nullptr, 0, Ch, 0}; return s;
  };
  auto upsrc = [](const float* hf, const bf16* hh, const float* skf, const bf16* skh,
                  const int* u, int nprev, int Ch, int Cs) {
    VSrc s{hf, hh, skf, skh, u, nprev, Ch, Cs}; return s;
  };

  // big layer: t1 gather + combine with inline (vectorized) t2 gather
  auto big = [&](const bf16* Xh, float* OUT, bf16* OUTh, int lvl, int n,
                 int Cin, int Cout, const float* Wq, const float* Bp, int smax) {
    int nb = ep.nbase[lvl];
    int t4p = (n >> 1) * (Cin >> 2);
    k_prop_flat<<<(t4p + 255) / 256, 256, 0, stream>>>(Xh, t1h, cnt, ell, nb, n, Cin);
    int grid = ((Cout + 63) / 64) * ((n + 15) / 16);
    if (smax)
      k_combine_big<1><<<grid, 256, 0, stream>>>(Xh, t1h, (const float4*)Wq, Bp, cnt, ell, nb, n, Cin, Cout, OUT, OUTh);
    else
      k_combine_big<0><<<grid, 256, 0, stream>>>(Xh, t1h, (const float4*)Wq, Bp, cnt, ell, nb, n, Cin, Cout, OUT, OUTh);
  };

  // mid layer: virtual prop + gather-combine with W batching (proven 517us tilings)
#define MID(RS, CWv, s, OUT, OUTh, lvl, n, Cin, Cout, Wq, Bp)                                   \
  {                                                                                             \
    int nb = ep.nbase[lvl];                                                                     \
    int t2n = (n) * ((Cin) >> 1);                                                               \
    k_prop_v<<<(t2n + 255) / 256, 256, 0, stream>>>(s, t1f, t1h, cnt, ell, nb, n, Cin);         \
    int grid = (((Cout) + 63) / 64) * (((n) + (RS)-1) / (RS));                                  \
    k_combine<RS, CWv><<<grid, 256, 0, stream>>>(s, t1f, t1h, (const float4*)Wq,                \
                                                 Bp, cnt, ell, nb, n, Cin, Cout, OUT, OUTh);    \
  }

  // ---- L1: n=40962, 4->32 ----
  big(x0h, af[0], ah[0], 5, 40962, 4, 32, wp[0], Bb[0], 0);
  // ---- L2: n=10242, 32->64 ----
  big(ah[0], af[1], ah[1], 4, 10242, 32, 64, wp[1], Bb[1], 0);
  // ---- mid encoder ----
  MID(4, 1, plain(af[1], ah[1], 64), af[2], ah[2], 3, 2562, 64, 128, wp[2], Bb[2]);
  MID(2, 2, plain(af[2], ah[2], 128), af[3], ah[3], 2, 642, 128, 256, wp[3], Bb[3]);
  MID(1, 4, plain(af[3], ah[3], 256), af[4], ah[4], 1, 162, 256, 512, wp[4], Bb[4]);
  MID(1, 4, plain(af[4], ah[4], 512), af[5], ah[5], 0, 42, 512, 512, wp[5], Bb[5]);
  // ---- mid decoder ----
  MID(1, 4, upsrc(af[5], ah[5], af[3], ah[3], up[0], 42, 512, 256), af[6], ah[6], 1, 162, 768, 256, wp[6], Bb[6]);
  MID(2, 4, upsrc(af[6], ah[6], af[2], ah[2], up[1], 162, 256, 128), af[7], ah[7], 2, 642, 384, 128, wp[7], Bb[7]);
  MID(2, 4, upsrc(af[7], ah[7], af[1], ah[1], up[2], 642, 128, 64), af[8], ah[8], 3, 2562, 192, 64, wp[8], Bb[8]);
  // ---- L10: n=10242, [64|32]->32 ----
  {
    VSrc s = upsrc(af[8], ah[8], af[0], ah[0], up[3], 2562, 64, 32);
    k_xmat<<<(10242 * 48 + 255) / 256, 256, 0, stream>>>(s, xh, 10242, 96);
    big(xh, af[9], ah[9], 4, 10242, 96, 32, wp[9], Bb[9], 0);
  }
  // ---- L11: n=40962, [32|4]->37 + softmax ----
  {
    VSrc s = upsrc(af[9], ah[9], x0f, x0h, up[4], 10242, 32, 4);
    k_xmat<<<(40962 * 18 + 255) / 256, 256, 0, stream>>>(s, xh, 40962, 36);
    big(xh, (float*)d_out, nullptr, 5, 40962, 36, 37, wp[10], Bb[10], 1);
  }
}